// Round 4
// baseline (1442.570 us; speedup 1.0000x reference)
//
#include <hip/hip_runtime.h>

#define HID 32
#define DLAT 97
#define NPG 100
#define TOPK 30
#define BKT_NODES 256   // nodes per bucket (bucket = dst >> 8)
#define MAXBKT 512      // >= ceil(N/256); N=100000 -> 391
#define EPB 4096        // edges per binning block

// ---------------- binning: partition edges by dst bucket ----------------

// per-block bucket histogram (no global atomics)
__global__ void binA_kernel(const int* __restrict__ dst, int* __restrict__ blockhist, int E) {
    __shared__ int hist[MAXBKT];
    for (int t = threadIdx.x; t < MAXBKT; t += blockDim.x) hist[t] = 0;
    __syncthreads();
    int base = blockIdx.x * EPB;
    int lim = min(E, base + EPB);
    for (int e = base + threadIdx.x; e < lim; e += blockDim.x)
        atomicAdd(&hist[dst[e] >> 8], 1);
    __syncthreads();
    for (int t = threadIdx.x; t < MAXBKT; t += blockDim.x)
        blockhist[(size_t)blockIdx.x * MAXBKT + t] = hist[t];
}

// column-wise exclusive scan of blockhist (in-place: becomes within-bucket offset
// for each block) + exclusive scan over bucket totals -> bucket_start
__global__ void binscan_kernel(int* __restrict__ blockhist, int* __restrict__ bucket_start,
                               int NB) {
    __shared__ int sh[MAXBKT];
    int t = threadIdx.x;  // MAXBKT threads
    int run = 0;
    for (int blk = 0; blk < NB; ++blk) {
        size_t idx = (size_t)blk * MAXBKT + t;
        int v = blockhist[idx];
        blockhist[idx] = run;
        run += v;
    }
    sh[t] = run;
    __syncthreads();
    for (int off = 1; off < MAXBKT; off <<= 1) {
        int tv = (t >= off) ? sh[t - off] : 0;
        __syncthreads();
        sh[t] += tv;
        __syncthreads();
    }
    bucket_start[t] = sh[t] - run;                 // exclusive
    if (t == MAXBKT - 1) bucket_start[MAXBKT] = sh[t];  // = E
}

// scatter into reserved ranges: packed {src | dstloc<<20, ew}
__global__ void binB_kernel(const int* __restrict__ src, const int* __restrict__ dst,
                            const float* __restrict__ ew, const int* __restrict__ blockhist,
                            const int* __restrict__ bucket_start, int2* __restrict__ bedge,
                            int E) {
    __shared__ int lcur[MAXBKT];
    for (int t = threadIdx.x; t < MAXBKT; t += blockDim.x)
        lcur[t] = bucket_start[t] + blockhist[(size_t)blockIdx.x * MAXBKT + t];
    __syncthreads();
    int base = blockIdx.x * EPB;
    int lim = min(E, base + EPB);
    for (int e = base + threadIdx.x; e < lim; e += blockDim.x) {
        int d = dst[e];
        int slot = atomicAdd(&lcur[d >> 8], 1);
        bedge[slot] = make_int2(src[e] | ((d & 255) << 20), __float_as_int(ew[e]));
    }
}

// ---------------- degree / dinv (bucketed, LDS accumulate) ----------------

__global__ void degdinv_kernel(const int* __restrict__ bucket_start,
                               const int2* __restrict__ bedge,
                               float* __restrict__ dinv, int N) {
    __shared__ float facc[BKT_NODES];
    if (threadIdx.x < BKT_NODES) facc[threadIdx.x] = 0.f;
    __syncthreads();
    int b = blockIdx.x;
    int beg = bucket_start[b], end = bucket_start[b + 1];
    for (int i = beg + threadIdx.x; i < end; i += blockDim.x) {
        int2 v = bedge[i];
        atomicAdd(&facc[v.x >> 20], __int_as_float(v.y));
    }
    __syncthreads();
    int n = b * BKT_NODES + threadIdx.x;
    if (threadIdx.x < BKT_NODES && n < N)
        dinv[n] = 1.0f / sqrtf(1.0f + facc[threadIdx.x]);
}

// ---------------- GCN xw GEMMs (scaled by dinv[n]) ----------------

// layer 1: xw[n][f] = dinv[n] * dot(z_emb[z[n]], W[:,f])
__global__ void xw1_kernel(const int* __restrict__ z, const float* __restrict__ z_emb,
                           const float* __restrict__ W, const float* __restrict__ dinv,
                           float* __restrict__ xw, int N) {
    int tid = blockIdx.x * blockDim.x + threadIdx.x;
    if (tid >= N * HID) return;
    int n = tid >> 5, f = tid & 31;
    const float* row = z_emb + (size_t)z[n] * HID;
    float s = 0.f;
#pragma unroll
    for (int k = 0; k < HID; ++k) s += row[k] * W[k * HID + f];
    xw[tid] = s * dinv[n];
}

// layers 2/3: input rows are concat[n*97 + off .. +32]
__global__ void xwl_kernel(const float* __restrict__ concat, int off,
                           const float* __restrict__ W, const float* __restrict__ dinv,
                           float* __restrict__ xw, int N) {
    int tid = blockIdx.x * blockDim.x + threadIdx.x;
    if (tid >= N * HID) return;
    int n = tid >> 5, f = tid & 31;
    const float* row = concat + (size_t)n * DLAT + off;
    float s = 0.f;
#pragma unroll
    for (int k = 0; k < HID; ++k) s += row[k] * W[k * HID + f];
    xw[tid] = s * dinv[n];
}

__global__ void xw4_kernel(const float* __restrict__ concat, const float* __restrict__ W4,
                           const float* __restrict__ dinv, float* __restrict__ xw4, int N) {
    int n = blockIdx.x * blockDim.x + threadIdx.x;
    if (n >= N) return;
    const float* row = concat + (size_t)n * DLAT + 64;
    float s = 0.f;
#pragma unroll
    for (int k = 0; k < HID; ++k) s += row[k] * W4[k];
    xw4[n] = s * dinv[n];
}

// ---------------- bucketed aggregation (LDS accumulator) ----------------

// out[n][f] = tanh(dinv[n]*(sum_e ew_e*xws[src_e][f] + xws[n][f]) + b[f])
// where xws is dinv-prescaled xw. Writes concat columns [col_off, col_off+32).
__global__ __launch_bounds__(256) void agg32_kernel(
    const int* __restrict__ bucket_start, const int2* __restrict__ bedge,
    const float* __restrict__ xw, const float* __restrict__ b,
    const float* __restrict__ dinv, float* __restrict__ concat, int col_off, int N) {
    __shared__ float acc[BKT_NODES * HID];  // 32 KB
    for (int t = threadIdx.x; t < BKT_NODES * HID; t += 256) acc[t] = 0.f;
    __syncthreads();
    int bkt = blockIdx.x;
    int beg = bucket_start[bkt];
    int M = bucket_start[bkt + 1] - beg;
    int wave = threadIdx.x >> 6;
    int lane = threadIdx.x & 63;
    int h = lane >> 5, f = lane & 31;
    // 4 waves x 2 edges per iteration; lanes f=0..31 span one xw row (128B dense)
#pragma unroll 4
    for (int i = wave * 2 + h; i < M; i += 8) {
        int2 v = bedge[beg + i];
        float xv = xw[(size_t)(v.x & 0xFFFFF) * HID + f];
        atomicAdd(&acc[(v.x >> 20) * HID + f], __int_as_float(v.y) * xv);
    }
    __syncthreads();
    int m0 = threadIdx.x >> 5;  // 8 nodes x 32 features per sweep (bank-conflict-free)
    int ff = threadIdx.x & 31;
    for (int m = m0; m < BKT_NODES; m += 8) {
        int n = bkt * BKT_NODES + m;
        if (n >= N) break;
        float di = dinv[n];
        float val = di * (acc[m * HID + ff] + xw[(size_t)n * HID + ff]) + b[ff];
        concat[(size_t)n * DLAT + col_off + ff] = tanhf(val);
    }
}

__global__ void agg1_kernel(const int* __restrict__ bucket_start, const int2* __restrict__ bedge,
                            const float* __restrict__ xw4, const float* __restrict__ b4,
                            const float* __restrict__ dinv, float* __restrict__ concat, int N) {
    __shared__ float facc[BKT_NODES];
    if (threadIdx.x < BKT_NODES) facc[threadIdx.x] = 0.f;
    __syncthreads();
    int b = blockIdx.x;
    int beg = bucket_start[b], end = bucket_start[b + 1];
    for (int i = beg + threadIdx.x; i < end; i += blockDim.x) {
        int2 v = bedge[i];
        atomicAdd(&facc[v.x >> 20], __int_as_float(v.y) * xw4[v.x & 0xFFFFF]);
    }
    __syncthreads();
    int n = b * BKT_NODES + threadIdx.x;
    if (threadIdx.x < BKT_NODES && n < N) {
        float di = dinv[n];
        concat[(size_t)n * DLAT + 96] = tanhf(di * (facc[threadIdx.x] + xw4[n]) + b4[0]);
    }
}

// ---- top-k: stable rank (matches jnp.argsort(-v) tie-break: lower index first) ----
__global__ void topk_kernel(const float* __restrict__ concat, int* __restrict__ top_idx) {
    int g = blockIdx.x;
    int tid = threadIdx.x;
    __shared__ float v[NPG];
    if (tid < NPG) v[tid] = concat[(size_t)(g * NPG + tid) * DLAT + 96];
    __syncthreads();
    if (tid < NPG) {
        float vi = v[tid];
        int cnt = 0;
#pragma unroll 4
        for (int j = 0; j < NPG; ++j) {
            float vj = v[j];
            cnt += (vj > vi) || (vj == vi && j < tid);
        }
        if (cnt < TOPK) top_idx[g * TOPK + cnt] = g * NPG + tid;
    }
}

// ---- head: conv1(97->16 per slot) -> maxpool2 -> conv1d(16->32,k5) -> fc(352->128) -> fc(128->1)
__global__ __launch_bounds__(128) void head_kernel(
    const float* __restrict__ concat, const int* __restrict__ top_idx,
    const float* __restrict__ Wc1, const float* __restrict__ bc1,
    const float* __restrict__ Wc2, const float* __restrict__ bc2,
    const float* __restrict__ Wl1, const float* __restrict__ bl1,
    const float* __restrict__ Wl2, const float* __restrict__ bl2,
    float* __restrict__ out) {
    int g = blockIdx.x;
    int tid = threadIdx.x;  // 128 threads
    __shared__ float top[TOPK * DLAT];
    __shared__ float y1[16 * TOPK];
    __shared__ float y2[16 * 15];
    __shared__ float y3[352];
    __shared__ float r[128];

    for (int idx = tid; idx < TOPK * DLAT; idx += 128) {
        int k = idx / DLAT, d = idx % DLAT;
        int node = top_idx[g * TOPK + k];
        top[idx] = concat[(size_t)node * DLAT + d];
    }
    __syncthreads();

    for (int idx = tid; idx < 16 * TOPK; idx += 128) {
        int c = idx / TOPK, k = idx % TOPK;
        float s = bc1[c];
        const float* w = Wc1 + c * DLAT;
        const float* t = top + k * DLAT;
#pragma unroll 4
        for (int d = 0; d < DLAT; ++d) s += t[d] * w[d];
        y1[c * TOPK + k] = fmaxf(s, 0.f);
    }
    __syncthreads();

    for (int idx = tid; idx < 16 * 15; idx += 128) {
        int c = idx / 15, j = idx % 15;
        y2[idx] = fmaxf(y1[c * TOPK + 2 * j], y1[c * TOPK + 2 * j + 1]);
    }
    __syncthreads();

    for (int idx = tid; idx < 352; idx += 128) {
        int o = idx / 11, t = idx % 11;
        float s = bc2[o];
#pragma unroll
        for (int i = 0; i < 16; ++i) {
#pragma unroll
            for (int k = 0; k < 5; ++k)
                s += Wc2[(o * 16 + i) * 5 + k] * y2[i * 15 + t + k];
        }
        y3[idx] = fmaxf(s, 0.f);
    }
    __syncthreads();

    {
        float s = bl1[tid];
        for (int d = 0; d < 352; ++d) s += y3[d] * Wl1[d * 128 + tid];
        r[tid] = fmaxf(s, 0.f) * Wl2[tid];
    }
    __syncthreads();
    if (tid < 64) r[tid] += r[tid + 64];
    __syncthreads();
    if (tid == 0) {
        float s = 0.f;
        for (int j = 0; j < 64; ++j) s += r[j];
        out[g] = s + bl2[0];
    }
}

// ---------------- launch ----------------

extern "C" void kernel_launch(void* const* d_in, const int* in_sizes, int n_in,
                              void* d_out, int out_size, void* d_ws, size_t ws_size,
                              hipStream_t stream) {
    const int* z = (const int*)d_in[0];
    const int* ei = (const int*)d_in[1];
    const float* ew = (const float*)d_in[3];
    const float* z_emb = (const float*)d_in[4];
    const float* Wg[4] = {(const float*)d_in[5], (const float*)d_in[7],
                          (const float*)d_in[9], (const float*)d_in[11]};
    const float* bg[4] = {(const float*)d_in[6], (const float*)d_in[8],
                          (const float*)d_in[10], (const float*)d_in[12]};
    const float* Wc1 = (const float*)d_in[13];
    const float* bc1 = (const float*)d_in[14];
    const float* Wc2 = (const float*)d_in[15];
    const float* bc2 = (const float*)d_in[16];
    const float* Wl1 = (const float*)d_in[17];
    const float* bl1 = (const float*)d_in[18];
    const float* Wl2 = (const float*)d_in[19];
    const float* bl2 = (const float*)d_in[20];
    float* out = (float*)d_out;

    const int N = in_sizes[0];
    const int E = in_sizes[1] / 2;
    const int G = out_size;  // 1000 graphs
    const int* src = ei;
    const int* dst = ei + E;

    auto cdiv = [](long long a, long long b) { return (int)((a + b - 1) / b); };
    const int NB = cdiv(E, EPB);            // binning blocks
    const int NBKT = cdiv(N, BKT_NODES);    // buckets (<= MAXBKT)

    // workspace layout (bedge first: 8B aligned)
    char* ws = (char*)d_ws;
    int2* bedge = (int2*)ws;                  ws += sizeof(int2) * (size_t)E;
    int* blockhist = (int*)ws;                ws += sizeof(int) * (size_t)NB * MAXBKT;
    int* bucket_start = (int*)ws;             ws += sizeof(int) * (MAXBKT + 1);
    float* dinv = (float*)ws;                 ws += sizeof(float) * N;
    float* xw = (float*)ws;                   ws += sizeof(float) * (size_t)N * HID;
    float* concat = (float*)ws;               ws += sizeof(float) * (size_t)N * DLAT;
    int* top_idx = (int*)ws;                  ws += sizeof(int) * G * TOPK;
    float* xw4 = xw;  // layer-4 reuses xw space

    const int B = 256;

    // bin edges by dst bucket (deterministic two-pass partition, no global atomics)
    binA_kernel<<<NB, B, 0, stream>>>(dst, blockhist, E);
    binscan_kernel<<<1, MAXBKT, 0, stream>>>(blockhist, bucket_start, NB);
    binB_kernel<<<NB, B, 0, stream>>>(src, dst, ew, blockhist, bucket_start, bedge, E);

    // degree -> dinv (bucketed LDS accumulation)
    degdinv_kernel<<<NBKT, B, 0, stream>>>(bucket_start, bedge, dinv, N);

    // GCN layers 1-3 (32-wide), tanh fused, outputs into concat columns
    xw1_kernel<<<cdiv((long long)N * HID, B), B, 0, stream>>>(z, z_emb, Wg[0], dinv, xw, N);
    agg32_kernel<<<NBKT, B, 0, stream>>>(bucket_start, bedge, xw, bg[0], dinv, concat, 0, N);
    for (int l = 1; l < 3; ++l) {
        xwl_kernel<<<cdiv((long long)N * HID, B), B, 0, stream>>>(
            concat, (l - 1) * HID, Wg[l], dinv, xw, N);
        agg32_kernel<<<NBKT, B, 0, stream>>>(bucket_start, bedge, xw, bg[l], dinv,
                                             concat, l * HID, N);
    }

    // layer 4 (width 1) -> concat column 96
    xw4_kernel<<<cdiv(N, B), B, 0, stream>>>(concat, Wg[3], dinv, xw4, N);
    agg1_kernel<<<NBKT, B, 0, stream>>>(bucket_start, bedge, xw4, bg[3], dinv, concat, N);

    // top-30 selection + CNN/MLP head
    topk_kernel<<<G, 128, 0, stream>>>(concat, top_idx);
    head_kernel<<<G, 128, 0, stream>>>(concat, top_idx, Wc1, bc1, Wc2, bc2,
                                       Wl1, bl1, Wl2, bl2, out);
}

// Round 5
// 606.153 us; speedup vs baseline: 2.3799x; 2.3799x over previous
//
#include <hip/hip_runtime.h>

#define HID 32
#define DLAT 97
#define NPG 100
#define TOPK 30
#define BKT_NODES 256   // nodes per bucket (bucket = dst >> 8)
#define MAXBKT 512      // >= ceil(N/256); N=100000 -> 391
#define EPB 4096        // edges per binning block

// ---------------- binning: partition edges by dst bucket ----------------

// per-block bucket histogram (no global atomics)
__global__ void binA_kernel(const int* __restrict__ dst, int* __restrict__ blockhist, int E) {
    __shared__ int hist[MAXBKT];
    for (int t = threadIdx.x; t < MAXBKT; t += blockDim.x) hist[t] = 0;
    __syncthreads();
    int base = blockIdx.x * EPB;
    int lim = min(E, base + EPB);
    for (int e = base + threadIdx.x; e < lim; e += blockDim.x)
        atomicAdd(&hist[dst[e] >> 8], 1);
    __syncthreads();
    for (int t = threadIdx.x; t < MAXBKT; t += blockDim.x)
        blockhist[(size_t)blockIdx.x * MAXBKT + t] = hist[t];
}

// column-wise exclusive scan of blockhist (in-place: per-block within-bucket base)
// + exclusive scan over bucket totals -> bucket_start
__global__ void binscan_kernel(int* __restrict__ blockhist, int* __restrict__ bucket_start,
                               int NB) {
    __shared__ int sh[MAXBKT];
    int t = threadIdx.x;  // MAXBKT threads
    int run = 0;
    int blk = 0;
    for (; blk + 4 <= NB; blk += 4) {  // unroll: overlap the 4 loads
        size_t i0 = (size_t)blk * MAXBKT + t;
        int v0 = blockhist[i0];
        int v1 = blockhist[i0 + MAXBKT];
        int v2 = blockhist[i0 + 2 * MAXBKT];
        int v3 = blockhist[i0 + 3 * MAXBKT];
        blockhist[i0] = run;
        blockhist[i0 + MAXBKT] = run + v0;
        blockhist[i0 + 2 * MAXBKT] = run + v0 + v1;
        blockhist[i0 + 3 * MAXBKT] = run + v0 + v1 + v2;
        run += v0 + v1 + v2 + v3;
    }
    for (; blk < NB; ++blk) {
        size_t idx = (size_t)blk * MAXBKT + t;
        int v = blockhist[idx];
        blockhist[idx] = run;
        run += v;
    }
    sh[t] = run;
    __syncthreads();
    for (int off = 1; off < MAXBKT; off <<= 1) {
        int tv = (t >= off) ? sh[t - off] : 0;
        __syncthreads();
        sh[t] += tv;
        __syncthreads();
    }
    bucket_start[t] = sh[t] - run;                      // exclusive
    if (t == MAXBKT - 1) bucket_start[MAXBKT] = sh[t];  // = E
}

// scatter into reserved ranges: packed {src | dstloc<<20, ew}
__global__ void binB_kernel(const int* __restrict__ src, const int* __restrict__ dst,
                            const float* __restrict__ ew, const int* __restrict__ blockhist,
                            const int* __restrict__ bucket_start, int2* __restrict__ bedge,
                            int E) {
    __shared__ int lcur[MAXBKT];
    for (int t = threadIdx.x; t < MAXBKT; t += blockDim.x)
        lcur[t] = bucket_start[t] + blockhist[(size_t)blockIdx.x * MAXBKT + t];
    __syncthreads();
    int base = blockIdx.x * EPB;
    int lim = min(E, base + EPB);
    for (int e = base + threadIdx.x; e < lim; e += blockDim.x) {
        int d = dst[e];
        int slot = atomicAdd(&lcur[d >> 8], 1);
        bedge[slot] = make_int2(src[e] | ((d & 255) << 20), __float_as_int(ew[e]));
    }
}

// per-bucket counting sort -> fully dst-sorted CSR {src, ew} + row_start
__global__ __launch_bounds__(BKT_NODES) void sortlocal_kernel(
    const int2* __restrict__ bedge, const int* __restrict__ bucket_start,
    int2* __restrict__ csr, int* __restrict__ row_start, int N, int E) {
    __shared__ int cnt[BKT_NODES];
    __shared__ int sh[BKT_NODES];
    __shared__ int lcur[BKT_NODES];
    int b = blockIdx.x;
    int beg = bucket_start[b], end = bucket_start[b + 1];
    int t = threadIdx.x;
    cnt[t] = 0;
    __syncthreads();
    for (int i = beg + t; i < end; i += BKT_NODES)
        atomicAdd(&cnt[bedge[i].x >> 20], 1);
    __syncthreads();
    int v = cnt[t];
    sh[t] = v;
    __syncthreads();
    for (int off = 1; off < BKT_NODES; off <<= 1) {
        int tv = (t >= off) ? sh[t - off] : 0;
        __syncthreads();
        sh[t] += tv;
        __syncthreads();
    }
    int excl = sh[t] - v;
    lcur[t] = excl;
    int n = b * BKT_NODES + t;
    if (n < N) row_start[n] = beg + excl;
    if (b == 0 && t == 0) row_start[N] = E;
    __syncthreads();
    for (int i = beg + t; i < end; i += BKT_NODES) {
        int2 e = bedge[i];
        int slot = atomicAdd(&lcur[e.x >> 20], 1);
        csr[beg + slot] = make_int2(e.x & 0xFFFFF, e.y);
    }
}

// deg[n] = 1 + sum(ew over row) -> dinv[n]  (sequential CSR reads)
__global__ void degdinv_kernel(const int* __restrict__ row_start, const int2* __restrict__ csr,
                               float* __restrict__ dinv, int N) {
    int n = blockIdx.x * blockDim.x + threadIdx.x;
    if (n >= N) return;
    int beg = row_start[n], end = row_start[n + 1];
    float s = 1.0f;
    for (int i = beg; i < end; ++i) s += __int_as_float(csr[i].y);
    dinv[n] = 1.0f / sqrtf(s);
}

// ---------------- GCN xw GEMMs (prescaled by dinv[n]) ----------------

__global__ void xw1_kernel(const int* __restrict__ z, const float* __restrict__ z_emb,
                           const float* __restrict__ W, const float* __restrict__ dinv,
                           float* __restrict__ xw, int N) {
    int tid = blockIdx.x * blockDim.x + threadIdx.x;
    if (tid >= N * HID) return;
    int n = tid >> 5, f = tid & 31;
    const float* row = z_emb + (size_t)z[n] * HID;
    float s = 0.f;
#pragma unroll
    for (int k = 0; k < HID; ++k) s += row[k] * W[k * HID + f];
    xw[tid] = s * dinv[n];
}

__global__ void xwl_kernel(const float* __restrict__ concat, int off,
                           const float* __restrict__ W, const float* __restrict__ dinv,
                           float* __restrict__ xw, int N) {
    int tid = blockIdx.x * blockDim.x + threadIdx.x;
    if (tid >= N * HID) return;
    int n = tid >> 5, f = tid & 31;
    const float* row = concat + (size_t)n * DLAT + off;
    float s = 0.f;
#pragma unroll
    for (int k = 0; k < HID; ++k) s += row[k] * W[k * HID + f];
    xw[tid] = s * dinv[n];
}

__global__ void xw4_kernel(const float* __restrict__ concat, const float* __restrict__ W4,
                           const float* __restrict__ dinv, float* __restrict__ xw4, int N) {
    int n = blockIdx.x * blockDim.x + threadIdx.x;
    if (n >= N) return;
    const float* row = concat + (size_t)n * DLAT + 64;
    float s = 0.f;
#pragma unroll
    for (int k = 0; k < HID; ++k) s += row[k] * W4[k];
    xw4[n] = s * dinv[n];
}

// ---------------- per-node CSR aggregation (high TLP) ----------------

// out[n][f] = tanh(dinv[n]*(sum_e ew_e*xws[src_e][f] + xws[n][f]) + b[f])
// 64 lanes per node: lane = 32*h + f; halves h=0/1 take alternating edges.
__global__ void agg32_kernel(const int* __restrict__ row_start, const int2* __restrict__ csr,
                             const float* __restrict__ xw, const float* __restrict__ b,
                             const float* __restrict__ dinv,
                             float* __restrict__ concat, int col_off, int N) {
    int tid = blockIdx.x * blockDim.x + threadIdx.x;
    int n = tid >> 6;
    if (n >= N) return;
    int lane = tid & 63;
    int h = lane >> 5, f = lane & 31;
    int beg = row_start[n], end = row_start[n + 1];
    float s = 0.f;
    for (int i = beg + h; i < end; i += 2) {
        int2 v = csr[i];
        s += __int_as_float(v.y) * xw[(size_t)v.x * HID + f];
    }
    s += __shfl_xor(s, 32);
    if (h == 0) {
        float di = dinv[n];
        float tot = di * (s + xw[(size_t)n * HID + f]) + b[f];
        concat[(size_t)n * DLAT + col_off + f] = tanhf(tot);
    }
}

__global__ void agg1_kernel(const int* __restrict__ row_start, const int2* __restrict__ csr,
                            const float* __restrict__ xw4, const float* __restrict__ b4,
                            const float* __restrict__ dinv, float* __restrict__ concat, int N) {
    int n = blockIdx.x * blockDim.x + threadIdx.x;
    if (n >= N) return;
    int beg = row_start[n], end = row_start[n + 1];
    float s = 0.f;
    for (int i = beg; i < end; ++i) {
        int2 v = csr[i];
        s += __int_as_float(v.y) * xw4[v.x];
    }
    float di = dinv[n];
    concat[(size_t)n * DLAT + 96] = tanhf(di * (s + xw4[n]) + b4[0]);
}

// ---- top-k: stable rank (matches jnp.argsort(-v) tie-break: lower index first) ----
__global__ void topk_kernel(const float* __restrict__ concat, int* __restrict__ top_idx) {
    int g = blockIdx.x;
    int tid = threadIdx.x;
    __shared__ float v[NPG];
    if (tid < NPG) v[tid] = concat[(size_t)(g * NPG + tid) * DLAT + 96];
    __syncthreads();
    if (tid < NPG) {
        float vi = v[tid];
        int cnt = 0;
#pragma unroll 4
        for (int j = 0; j < NPG; ++j) {
            float vj = v[j];
            cnt += (vj > vi) || (vj == vi && j < tid);
        }
        if (cnt < TOPK) top_idx[g * TOPK + cnt] = g * NPG + tid;
    }
}

// ---- head: conv1(97->16 per slot) -> maxpool2 -> conv1d(16->32,k5) -> fc(352->128) -> fc(128->1)
__global__ __launch_bounds__(128) void head_kernel(
    const float* __restrict__ concat, const int* __restrict__ top_idx,
    const float* __restrict__ Wc1, const float* __restrict__ bc1,
    const float* __restrict__ Wc2, const float* __restrict__ bc2,
    const float* __restrict__ Wl1, const float* __restrict__ bl1,
    const float* __restrict__ Wl2, const float* __restrict__ bl2,
    float* __restrict__ out) {
    int g = blockIdx.x;
    int tid = threadIdx.x;  // 128 threads
    __shared__ float top[TOPK * DLAT];
    __shared__ float y1[16 * TOPK];
    __shared__ float y2[16 * 15];
    __shared__ float y3[352];
    __shared__ float r[128];

    for (int idx = tid; idx < TOPK * DLAT; idx += 128) {
        int k = idx / DLAT, d = idx % DLAT;
        int node = top_idx[g * TOPK + k];
        top[idx] = concat[(size_t)node * DLAT + d];
    }
    __syncthreads();

    for (int idx = tid; idx < 16 * TOPK; idx += 128) {
        int c = idx / TOPK, k = idx % TOPK;
        float s = bc1[c];
        const float* w = Wc1 + c * DLAT;
        const float* t = top + k * DLAT;
#pragma unroll 4
        for (int d = 0; d < DLAT; ++d) s += t[d] * w[d];
        y1[c * TOPK + k] = fmaxf(s, 0.f);
    }
    __syncthreads();

    for (int idx = tid; idx < 16 * 15; idx += 128) {
        int c = idx / 15, j = idx % 15;
        y2[idx] = fmaxf(y1[c * TOPK + 2 * j], y1[c * TOPK + 2 * j + 1]);
    }
    __syncthreads();

    for (int idx = tid; idx < 352; idx += 128) {
        int o = idx / 11, t = idx % 11;
        float s = bc2[o];
#pragma unroll
        for (int i = 0; i < 16; ++i) {
#pragma unroll
            for (int k = 0; k < 5; ++k)
                s += Wc2[(o * 16 + i) * 5 + k] * y2[i * 15 + t + k];
        }
        y3[idx] = fmaxf(s, 0.f);
    }
    __syncthreads();

    {
        float s = bl1[tid];
        for (int d = 0; d < 352; ++d) s += y3[d] * Wl1[d * 128 + tid];
        r[tid] = fmaxf(s, 0.f) * Wl2[tid];
    }
    __syncthreads();
    if (tid < 64) r[tid] += r[tid + 64];
    __syncthreads();
    if (tid == 0) {
        float s = 0.f;
        for (int j = 0; j < 64; ++j) s += r[j];
        out[g] = s + bl2[0];
    }
}

// ---------------- launch ----------------

extern "C" void kernel_launch(void* const* d_in, const int* in_sizes, int n_in,
                              void* d_out, int out_size, void* d_ws, size_t ws_size,
                              hipStream_t stream) {
    const int* z = (const int*)d_in[0];
    const int* ei = (const int*)d_in[1];
    const float* ew = (const float*)d_in[3];
    const float* z_emb = (const float*)d_in[4];
    const float* Wg[4] = {(const float*)d_in[5], (const float*)d_in[7],
                          (const float*)d_in[9], (const float*)d_in[11]};
    const float* bg[4] = {(const float*)d_in[6], (const float*)d_in[8],
                          (const float*)d_in[10], (const float*)d_in[12]};
    const float* Wc1 = (const float*)d_in[13];
    const float* bc1 = (const float*)d_in[14];
    const float* Wc2 = (const float*)d_in[15];
    const float* bc2 = (const float*)d_in[16];
    const float* Wl1 = (const float*)d_in[17];
    const float* bl1 = (const float*)d_in[18];
    const float* Wl2 = (const float*)d_in[19];
    const float* bl2 = (const float*)d_in[20];
    float* out = (float*)d_out;

    const int N = in_sizes[0];
    const int E = in_sizes[1] / 2;
    const int G = out_size;  // 1000 graphs
    const int* src = ei;
    const int* dst = ei + E;

    auto cdiv = [](long long a, long long b) { return (int)((a + b - 1) / b); };
    const int NB = cdiv(E, EPB);            // binning blocks
    const int NBKT = cdiv(N, BKT_NODES);    // buckets (<= MAXBKT)

    // workspace layout (8B-aligned arrays first)
    char* ws = (char*)d_ws;
    int2* bedge = (int2*)ws;                  ws += sizeof(int2) * (size_t)E;
    int2* csr = (int2*)ws;                    ws += sizeof(int2) * (size_t)E;
    int* blockhist = (int*)ws;                ws += sizeof(int) * (size_t)NB * MAXBKT;
    int* bucket_start = (int*)ws;             ws += sizeof(int) * (MAXBKT + 1);
    int* row_start = (int*)ws;                ws += sizeof(int) * (N + 1);
    float* dinv = (float*)ws;                 ws += sizeof(float) * N;
    float* xw = (float*)ws;                   ws += sizeof(float) * (size_t)N * HID;
    float* concat = (float*)ws;               ws += sizeof(float) * (size_t)N * DLAT;
    int* top_idx = (int*)ws;                  ws += sizeof(int) * G * TOPK;
    float* xw4 = xw;  // layer-4 reuses xw space

    const int B = 256;

    // deterministic two-level sort: bucket partition + per-bucket counting sort
    binA_kernel<<<NB, B, 0, stream>>>(dst, blockhist, E);
    binscan_kernel<<<1, MAXBKT, 0, stream>>>(blockhist, bucket_start, NB);
    binB_kernel<<<NB, B, 0, stream>>>(src, dst, ew, blockhist, bucket_start, bedge, E);
    sortlocal_kernel<<<NBKT, BKT_NODES, 0, stream>>>(bedge, bucket_start, csr, row_start, N, E);

    // degree -> dinv
    degdinv_kernel<<<cdiv(N, B), B, 0, stream>>>(row_start, csr, dinv, N);

    // GCN layers 1-3 (32-wide), tanh fused, outputs into concat columns
    xw1_kernel<<<cdiv((long long)N * HID, B), B, 0, stream>>>(z, z_emb, Wg[0], dinv, xw, N);
    agg32_kernel<<<cdiv((long long)N * 64, B), B, 0, stream>>>(
        row_start, csr, xw, bg[0], dinv, concat, 0, N);
    for (int l = 1; l < 3; ++l) {
        xwl_kernel<<<cdiv((long long)N * HID, B), B, 0, stream>>>(
            concat, (l - 1) * HID, Wg[l], dinv, xw, N);
        agg32_kernel<<<cdiv((long long)N * 64, B), B, 0, stream>>>(
            row_start, csr, xw, bg[l], dinv, concat, l * HID, N);
    }

    // layer 4 (width 1) -> concat column 96
    xw4_kernel<<<cdiv(N, B), B, 0, stream>>>(concat, Wg[3], dinv, xw4, N);
    agg1_kernel<<<cdiv(N, B), B, 0, stream>>>(row_start, csr, xw4, bg[3], dinv, concat, N);

    // top-30 selection + CNN/MLP head
    topk_kernel<<<G, 128, 0, stream>>>(concat, top_idx);
    head_kernel<<<G, 128, 0, stream>>>(concat, top_idx, Wc1, bc1, Wc2, bc2,
                                       Wl1, bl1, Wl2, bl2, out);
}

// Round 6
// 469.772 us; speedup vs baseline: 3.0708x; 1.2903x over previous
//
#include <hip/hip_runtime.h>

#define HID 32
#define DLAT 97
#define NPG 100
#define TOPK 30
#define BKT_NODES 256   // nodes per bucket (bucket = dst >> 8)
#define MAXBKT 512      // >= ceil(N/256); N=100000 -> 391
#define EPB 4096        // edges per binning block

// ---------------- binning: partition edges by dst bucket ----------------

__global__ void binA_kernel(const int* __restrict__ dst, int* __restrict__ blockhist, int E) {
    __shared__ int hist[MAXBKT];
    for (int t = threadIdx.x; t < MAXBKT; t += blockDim.x) hist[t] = 0;
    __syncthreads();
    int base = blockIdx.x * EPB;
    int lim = min(E, base + EPB);
    for (int e = base + threadIdx.x; e < lim; e += blockDim.x)
        atomicAdd(&hist[dst[e] >> 8], 1);
    __syncthreads();
    for (int t = threadIdx.x; t < MAXBKT; t += blockDim.x)
        blockhist[(size_t)blockIdx.x * MAXBKT + t] = hist[t];
}

__global__ void binscan_kernel(int* __restrict__ blockhist, int* __restrict__ bucket_start,
                               int NB) {
    __shared__ int sh[MAXBKT];
    int t = threadIdx.x;  // MAXBKT threads
    int run = 0;
    int blk = 0;
    for (; blk + 4 <= NB; blk += 4) {
        size_t i0 = (size_t)blk * MAXBKT + t;
        int v0 = blockhist[i0];
        int v1 = blockhist[i0 + MAXBKT];
        int v2 = blockhist[i0 + 2 * MAXBKT];
        int v3 = blockhist[i0 + 3 * MAXBKT];
        blockhist[i0] = run;
        blockhist[i0 + MAXBKT] = run + v0;
        blockhist[i0 + 2 * MAXBKT] = run + v0 + v1;
        blockhist[i0 + 3 * MAXBKT] = run + v0 + v1 + v2;
        run += v0 + v1 + v2 + v3;
    }
    for (; blk < NB; ++blk) {
        size_t idx = (size_t)blk * MAXBKT + t;
        int v = blockhist[idx];
        blockhist[idx] = run;
        run += v;
    }
    sh[t] = run;
    __syncthreads();
    for (int off = 1; off < MAXBKT; off <<= 1) {
        int tv = (t >= off) ? sh[t - off] : 0;
        __syncthreads();
        sh[t] += tv;
        __syncthreads();
    }
    bucket_start[t] = sh[t] - run;
    if (t == MAXBKT - 1) bucket_start[MAXBKT] = sh[t];
}

__global__ void binB_kernel(const int* __restrict__ src, const int* __restrict__ dst,
                            const float* __restrict__ ew, const int* __restrict__ blockhist,
                            const int* __restrict__ bucket_start, int2* __restrict__ bedge,
                            int E) {
    __shared__ int lcur[MAXBKT];
    for (int t = threadIdx.x; t < MAXBKT; t += blockDim.x)
        lcur[t] = bucket_start[t] + blockhist[(size_t)blockIdx.x * MAXBKT + t];
    __syncthreads();
    int base = blockIdx.x * EPB;
    int lim = min(E, base + EPB);
    for (int e = base + threadIdx.x; e < lim; e += blockDim.x) {
        int d = dst[e];
        int slot = atomicAdd(&lcur[d >> 8], 1);
        bedge[slot] = make_int2(src[e] | ((d & 255) << 20), __float_as_int(ew[e]));
    }
}

// per-bucket counting sort -> dst-sorted CSR {src, ew} + row_start
__global__ __launch_bounds__(BKT_NODES) void sortlocal_kernel(
    const int2* __restrict__ bedge, const int* __restrict__ bucket_start,
    int2* __restrict__ csr, int* __restrict__ row_start, int N, int E) {
    __shared__ int cnt[BKT_NODES];
    __shared__ int sh[BKT_NODES];
    __shared__ int lcur[BKT_NODES];
    int b = blockIdx.x;
    int beg = bucket_start[b], end = bucket_start[b + 1];
    int t = threadIdx.x;
    cnt[t] = 0;
    __syncthreads();
    for (int i = beg + t; i < end; i += BKT_NODES)
        atomicAdd(&cnt[bedge[i].x >> 20], 1);
    __syncthreads();
    int v = cnt[t];
    sh[t] = v;
    __syncthreads();
    for (int off = 1; off < BKT_NODES; off <<= 1) {
        int tv = (t >= off) ? sh[t - off] : 0;
        __syncthreads();
        sh[t] += tv;
        __syncthreads();
    }
    int excl = sh[t] - v;
    lcur[t] = excl;
    int n = b * BKT_NODES + t;
    if (n < N) row_start[n] = beg + excl;
    if (b == 0 && t == 0) row_start[N] = E;
    __syncthreads();
    for (int i = beg + t; i < end; i += BKT_NODES) {
        int2 e = bedge[i];
        int slot = atomicAdd(&lcur[e.x >> 20], 1);
        csr[beg + slot] = make_int2(e.x & 0xFFFFF, e.y);
    }
}

// deg[n] = 1 + sum(ew) -> dinv[n]
__global__ void degdinv_kernel(const int* __restrict__ row_start, const int2* __restrict__ csr,
                               float* __restrict__ dinv, int N) {
    int n = blockIdx.x * blockDim.x + threadIdx.x;
    if (n >= N) return;
    int beg = row_start[n], end = row_start[n + 1];
    float s = 1.0f;
    for (int i = beg; i < end; ++i) s += __int_as_float(csr[i].y);
    dinv[n] = 1.0f / sqrtf(s);
}

// layer 1: xw[n][f] = dinv[n] * dot(z_emb[z[n]], W[:,f])
__global__ void xw1_kernel(const int* __restrict__ z, const float* __restrict__ z_emb,
                           const float* __restrict__ W, const float* __restrict__ dinv,
                           float* __restrict__ xw, int N) {
    int tid = blockIdx.x * blockDim.x + threadIdx.x;
    if (tid >= N * HID) return;
    int n = tid >> 5, f = tid & 31;
    const float* row = z_emb + (size_t)z[n] * HID;
    float s = 0.f;
#pragma unroll
    for (int k = 0; k < HID; ++k) s += row[k] * W[k * HID + f];
    xw[tid] = s * dinv[n];
}

// ---------------- fused aggregation + next-layer xw GEMM ----------------
// out[n][f] = tanh(dinv[n]*(sum_e ew_e*xws[src_e][f] + xws[n][f]) + b[f])
// MODE==0: xw_next[n][f'] = dinv[n]*sum_k out[k]*Wn[k][f']   (Wn 32x32)
// MODE==1: xw_next[n]     = dinv[n]*sum_k out[k]*Wn[k]       (Wn 32, layer-4 input)
// Wave layout: 64 lanes per node; f = lane&31, halves h=0/1 take contiguous
// sub-ranges of the edge list; 4-deep unrolled gathers for MLP.
template <int MODE>
__global__ void agg32f_kernel(const int* __restrict__ row_start, const int2* __restrict__ csr,
                              const float* __restrict__ xw, const float* __restrict__ b,
                              const float* __restrict__ dinv, const float* __restrict__ Wn,
                              float* __restrict__ concat, int col_off,
                              float* __restrict__ xw_next, int N) {
    int tid = blockIdx.x * blockDim.x + threadIdx.x;
    int n = tid >> 6;
    if (n >= N) return;
    int lane = threadIdx.x & 63;
    int h = lane >> 5, f = lane & 31;
    int beg = row_start[n], end = row_start[n + 1];
    int len = end - beg;
    int mid = beg + ((len + 1) >> 1);
    int i = h ? mid : beg;
    int i1 = h ? end : mid;
    float s0 = 0.f, s1 = 0.f;
    for (; i + 3 < i1; i += 4) {
        int2 v0 = csr[i];
        int2 v1 = csr[i + 1];
        int2 v2 = csr[i + 2];
        int2 v3 = csr[i + 3];
        float x0 = xw[(size_t)v0.x * HID + f];
        float x1 = xw[(size_t)v1.x * HID + f];
        float x2 = xw[(size_t)v2.x * HID + f];
        float x3 = xw[(size_t)v3.x * HID + f];
        s0 += __int_as_float(v0.y) * x0;
        s1 += __int_as_float(v1.y) * x1;
        s0 += __int_as_float(v2.y) * x2;
        s1 += __int_as_float(v3.y) * x3;
    }
    for (; i < i1; ++i) {
        int2 v = csr[i];
        s0 += __int_as_float(v.y) * xw[(size_t)v.x * HID + f];
    }
    float s = s0 + s1;
    s += __shfl_xor(s, 32);  // both halves now hold the full edge sum
    float di = dinv[n];
    float outv = tanhf(di * (s + xw[(size_t)n * HID + f]) + b[f]);
    if (h == 0) concat[(size_t)n * DLAT + col_off + f] = outv;

    if (MODE == 0) {
        // next xw: each half sums its 16-k range, then combine across halves
        float p = 0.f;
#pragma unroll
        for (int kk = 0; kk < 16; ++kk) {
            int k = (h << 4) + kk;
            float ok = __shfl(outv, k);  // lane k (first half) holds out[k]
            p += ok * Wn[k * HID + f];
        }
        p += __shfl_xor(p, 32);
        if (h == 0) xw_next[(size_t)n * HID + f] = p * di;
    } else {
        // width-1 next layer: reduce out[f]*Wn[f] over f
        float p = outv * Wn[f];
        p += __shfl_xor(p, 16);
        p += __shfl_xor(p, 8);
        p += __shfl_xor(p, 4);
        p += __shfl_xor(p, 2);
        p += __shfl_xor(p, 1);
        if (lane == 0) xw_next[n] = p * di;
    }
}

// ---- fused layer-4 aggregation + tanh + stable top-k (per graph) ----
__global__ __launch_bounds__(128) void topk_kernel(
    const int* __restrict__ row_start, const int2* __restrict__ csr,
    const float* __restrict__ xw4, const float* __restrict__ b4,
    const float* __restrict__ dinv, int* __restrict__ top_idx,
    float* __restrict__ top_val) {
    int g = blockIdx.x;
    int tid = threadIdx.x;
    __shared__ float v[NPG];
    if (tid < NPG) {
        int n = g * NPG + tid;
        int beg = row_start[n], end = row_start[n + 1];
        float s = 0.f;
        for (int i = beg; i < end; ++i) {
            int2 e = csr[i];
            s += __int_as_float(e.y) * xw4[e.x];  // xw4: 400 KB, L2-resident
        }
        v[tid] = tanhf(dinv[n] * (s + xw4[n]) + b4[0]);
    }
    __syncthreads();
    if (tid < NPG) {
        float vi = v[tid];
        int cnt = 0;
#pragma unroll 4
        for (int j = 0; j < NPG; ++j) {
            float vj = v[j];
            cnt += (vj > vi) || (vj == vi && j < tid);
        }
        if (cnt < TOPK) {
            top_idx[g * TOPK + cnt] = g * NPG + tid;
            top_val[g * TOPK + cnt] = vi;
        }
    }
}

// ---- head: conv1(97->16) -> maxpool2 -> conv1d(16->32,k5) -> fc(352->128) -> fc(128->1)
__global__ __launch_bounds__(128) void head_kernel(
    const float* __restrict__ concat, const int* __restrict__ top_idx,
    const float* __restrict__ top_val,
    const float* __restrict__ Wc1, const float* __restrict__ bc1,
    const float* __restrict__ Wc2, const float* __restrict__ bc2,
    const float* __restrict__ Wl1, const float* __restrict__ bl1,
    const float* __restrict__ Wl2, const float* __restrict__ bl2,
    float* __restrict__ out) {
    int g = blockIdx.x;
    int tid = threadIdx.x;  // 128 threads
    __shared__ float top[TOPK * DLAT];
    __shared__ float y1[16 * TOPK];
    __shared__ float y2[16 * 15];
    __shared__ float y3[352];
    __shared__ float r[128];

    for (int idx = tid; idx < TOPK * DLAT; idx += 128) {
        int k = idx / DLAT, d = idx - k * DLAT;
        top[idx] = (d == 96) ? top_val[g * TOPK + k]
                             : concat[(size_t)top_idx[g * TOPK + k] * DLAT + d];
    }
    __syncthreads();

    for (int idx = tid; idx < 16 * TOPK; idx += 128) {
        int c = idx / TOPK, k = idx % TOPK;
        float s = bc1[c];
        const float* w = Wc1 + c * DLAT;
        const float* t = top + k * DLAT;
#pragma unroll 4
        for (int d = 0; d < DLAT; ++d) s += t[d] * w[d];
        y1[c * TOPK + k] = fmaxf(s, 0.f);
    }
    __syncthreads();

    for (int idx = tid; idx < 16 * 15; idx += 128) {
        int c = idx / 15, j = idx % 15;
        y2[idx] = fmaxf(y1[c * TOPK + 2 * j], y1[c * TOPK + 2 * j + 1]);
    }
    __syncthreads();

    for (int idx = tid; idx < 352; idx += 128) {
        int o = idx / 11, t = idx % 11;
        float s = bc2[o];
#pragma unroll
        for (int i = 0; i < 16; ++i) {
#pragma unroll
            for (int k = 0; k < 5; ++k)
                s += Wc2[(o * 16 + i) * 5 + k] * y2[i * 15 + t + k];
        }
        y3[idx] = fmaxf(s, 0.f);
    }
    __syncthreads();

    {
        float s = bl1[tid];
        for (int d = 0; d < 352; ++d) s += y3[d] * Wl1[d * 128 + tid];
        r[tid] = fmaxf(s, 0.f) * Wl2[tid];
    }
    __syncthreads();
    if (tid < 64) r[tid] += r[tid + 64];
    __syncthreads();
    if (tid == 0) {
        float s = 0.f;
        for (int j = 0; j < 64; ++j) s += r[j];
        out[g] = s + bl2[0];
    }
}

// ---------------- launch ----------------

extern "C" void kernel_launch(void* const* d_in, const int* in_sizes, int n_in,
                              void* d_out, int out_size, void* d_ws, size_t ws_size,
                              hipStream_t stream) {
    const int* z = (const int*)d_in[0];
    const int* ei = (const int*)d_in[1];
    const float* ew = (const float*)d_in[3];
    const float* z_emb = (const float*)d_in[4];
    const float* Wg[4] = {(const float*)d_in[5], (const float*)d_in[7],
                          (const float*)d_in[9], (const float*)d_in[11]};
    const float* bg[4] = {(const float*)d_in[6], (const float*)d_in[8],
                          (const float*)d_in[10], (const float*)d_in[12]};
    const float* Wc1 = (const float*)d_in[13];
    const float* bc1 = (const float*)d_in[14];
    const float* Wc2 = (const float*)d_in[15];
    const float* bc2 = (const float*)d_in[16];
    const float* Wl1 = (const float*)d_in[17];
    const float* bl1 = (const float*)d_in[18];
    const float* Wl2 = (const float*)d_in[19];
    const float* bl2 = (const float*)d_in[20];
    float* out = (float*)d_out;

    const int N = in_sizes[0];
    const int E = in_sizes[1] / 2;
    const int G = out_size;  // 1000 graphs
    const int* src = ei;
    const int* dst = ei + E;

    auto cdiv = [](long long a, long long b) { return (int)((a + b - 1) / b); };
    const int NB = cdiv(E, EPB);
    const int NBKT = cdiv(N, BKT_NODES);

    // workspace layout (8B-aligned arrays first)
    char* ws = (char*)d_ws;
    int2* bedge = (int2*)ws;                  ws += sizeof(int2) * (size_t)E;
    int2* csr = (int2*)ws;                    ws += sizeof(int2) * (size_t)E;
    int* blockhist = (int*)ws;                ws += sizeof(int) * (size_t)NB * MAXBKT;
    int* bucket_start = (int*)ws;             ws += sizeof(int) * (MAXBKT + 1);
    int* row_start = (int*)ws;                ws += sizeof(int) * (N + 1);
    float* dinv = (float*)ws;                 ws += sizeof(float) * N;
    float* xw_a = (float*)ws;                 ws += sizeof(float) * (size_t)N * HID;
    float* concat = (float*)ws;               ws += sizeof(float) * (size_t)N * DLAT;
    int* top_idx = (int*)ws;                  ws += sizeof(int) * G * TOPK;
    float* top_val = (float*)ws;              ws += sizeof(float) * G * TOPK;
    float* xw4 = (float*)ws;                  ws += sizeof(float) * N;
    // xw ping-pong: B-buffer aliases bedge (dead after sortlocal; N*128B == E*8B)
    float* xw_b = (float*)bedge;

    const int B = 256;

    // deterministic two-level sort: bucket partition + per-bucket counting sort
    binA_kernel<<<NB, B, 0, stream>>>(dst, blockhist, E);
    binscan_kernel<<<1, MAXBKT, 0, stream>>>(blockhist, bucket_start, NB);
    binB_kernel<<<NB, B, 0, stream>>>(src, dst, ew, blockhist, bucket_start, bedge, E);
    sortlocal_kernel<<<NBKT, BKT_NODES, 0, stream>>>(bedge, bucket_start, csr, row_start, N, E);

    // degree -> dinv
    degdinv_kernel<<<cdiv(N, B), B, 0, stream>>>(row_start, csr, dinv, N);

    // layer-1 xw, then fused agg+next-xw chain
    xw1_kernel<<<cdiv((long long)N * HID, B), B, 0, stream>>>(z, z_emb, Wg[0], dinv, xw_a, N);
    const int AGGB = cdiv((long long)N * 64, B);
    agg32f_kernel<0><<<AGGB, B, 0, stream>>>(row_start, csr, xw_a, bg[0], dinv, Wg[1],
                                             concat, 0, xw_b, N);
    agg32f_kernel<0><<<AGGB, B, 0, stream>>>(row_start, csr, xw_b, bg[1], dinv, Wg[2],
                                             concat, 32, xw_a, N);
    agg32f_kernel<1><<<AGGB, B, 0, stream>>>(row_start, csr, xw_a, bg[2], dinv, Wg[3],
                                             concat, 64, xw4, N);

    // fused layer-4 agg + tanh + top-30, then head
    topk_kernel<<<G, 128, 0, stream>>>(row_start, csr, xw4, bg[3], dinv, top_idx, top_val);
    head_kernel<<<G, 128, 0, stream>>>(concat, top_idx, top_val, Wc1, bc1, Wc2, bc2,
                                       Wl1, bl1, Wl2, bl2, out);
}

// Round 7
// 425.490 us; speedup vs baseline: 3.3904x; 1.1041x over previous
//
#include <hip/hip_runtime.h>

#define HID 32
#define DLAT 97
#define NPG 100
#define TOPK 30
#define BKT_NODES 256   // nodes per bucket (bucket = dst >> 8)
#define MAXBKT 512      // >= ceil(N/256); N=100000 -> 391
#define EPB 4096        // edges per binning block

// ---------------- binning: partition edges by dst bucket ----------------

__global__ void binA_kernel(const int* __restrict__ dst, int* __restrict__ blockhist, int E) {
    __shared__ int hist[MAXBKT];
    for (int t = threadIdx.x; t < MAXBKT; t += blockDim.x) hist[t] = 0;
    __syncthreads();
    int base = blockIdx.x * EPB;
    int lim = min(E, base + EPB);
    for (int e = base + threadIdx.x; e < lim; e += blockDim.x)
        atomicAdd(&hist[dst[e] >> 8], 1);
    __syncthreads();
    for (int t = threadIdx.x; t < MAXBKT; t += blockDim.x)
        blockhist[(size_t)blockIdx.x * MAXBKT + t] = hist[t];
}

__global__ void binscan_kernel(int* __restrict__ blockhist, int* __restrict__ bucket_start,
                               int NB) {
    __shared__ int sh[MAXBKT];
    int t = threadIdx.x;  // MAXBKT threads
    int run = 0;
    int blk = 0;
    for (; blk + 4 <= NB; blk += 4) {
        size_t i0 = (size_t)blk * MAXBKT + t;
        int v0 = blockhist[i0];
        int v1 = blockhist[i0 + MAXBKT];
        int v2 = blockhist[i0 + 2 * MAXBKT];
        int v3 = blockhist[i0 + 3 * MAXBKT];
        blockhist[i0] = run;
        blockhist[i0 + MAXBKT] = run + v0;
        blockhist[i0 + 2 * MAXBKT] = run + v0 + v1;
        blockhist[i0 + 3 * MAXBKT] = run + v0 + v1 + v2;
        run += v0 + v1 + v2 + v3;
    }
    for (; blk < NB; ++blk) {
        size_t idx = (size_t)blk * MAXBKT + t;
        int v = blockhist[idx];
        blockhist[idx] = run;
        run += v;
    }
    sh[t] = run;
    __syncthreads();
    for (int off = 1; off < MAXBKT; off <<= 1) {
        int tv = (t >= off) ? sh[t - off] : 0;
        __syncthreads();
        sh[t] += tv;
        __syncthreads();
    }
    bucket_start[t] = sh[t] - run;
    if (t == MAXBKT - 1) bucket_start[MAXBKT] = sh[t];
}

__global__ void binB_kernel(const int* __restrict__ src, const int* __restrict__ dst,
                            const float* __restrict__ ew, const int* __restrict__ blockhist,
                            const int* __restrict__ bucket_start, int2* __restrict__ bedge,
                            int E) {
    __shared__ int lcur[MAXBKT];
    for (int t = threadIdx.x; t < MAXBKT; t += blockDim.x)
        lcur[t] = bucket_start[t] + blockhist[(size_t)blockIdx.x * MAXBKT + t];
    __syncthreads();
    int base = blockIdx.x * EPB;
    int lim = min(E, base + EPB);
    for (int e = base + threadIdx.x; e < lim; e += blockDim.x) {
        int d = dst[e];
        int slot = atomicAdd(&lcur[d >> 8], 1);
        bedge[slot] = make_int2(src[e] | ((d & 255) << 20), __float_as_int(ew[e]));
    }
}

// per-bucket counting sort -> dst-sorted CSR {src, ew} + row_start + dinv (fused)
__global__ __launch_bounds__(BKT_NODES) void sortlocal_kernel(
    const int2* __restrict__ bedge, const int* __restrict__ bucket_start,
    int2* __restrict__ csr, int* __restrict__ row_start, float* __restrict__ dinv,
    int N, int E) {
    __shared__ int cnt[BKT_NODES];
    __shared__ float facc[BKT_NODES];
    __shared__ int sh[BKT_NODES];
    __shared__ int lcur[BKT_NODES];
    int b = blockIdx.x;
    int beg = bucket_start[b], end = bucket_start[b + 1];
    int t = threadIdx.x;
    cnt[t] = 0;
    facc[t] = 0.f;
    __syncthreads();
    for (int i = beg + t; i < end; i += BKT_NODES) {
        int2 e = bedge[i];
        int loc = e.x >> 20;
        atomicAdd(&cnt[loc], 1);
        atomicAdd(&facc[loc], __int_as_float(e.y));
    }
    __syncthreads();
    int n = b * BKT_NODES + t;
    if (n < N) dinv[n] = 1.0f / sqrtf(1.0f + facc[t]);  // deg = 1 + sum(ew)
    int v = cnt[t];
    sh[t] = v;
    __syncthreads();
    for (int off = 1; off < BKT_NODES; off <<= 1) {
        int tv = (t >= off) ? sh[t - off] : 0;
        __syncthreads();
        sh[t] += tv;
        __syncthreads();
    }
    int excl = sh[t] - v;
    lcur[t] = excl;
    if (n < N) row_start[n] = beg + excl;
    if (b == 0 && t == 0) row_start[N] = E;
    __syncthreads();
    for (int i = beg + t; i < end; i += BKT_NODES) {
        int2 e = bedge[i];
        int slot = atomicAdd(&lcur[e.x >> 20], 1);
        csr[beg + slot] = make_int2(e.x & 0xFFFFF, e.y);
    }
}

// layer 1: xw[n][f] = dinv[n] * dot(z_emb[z[n]], W[:,f])
__global__ void xw1_kernel(const int* __restrict__ z, const float* __restrict__ z_emb,
                           const float* __restrict__ W, const float* __restrict__ dinv,
                           float* __restrict__ xw, int N) {
    int tid = blockIdx.x * blockDim.x + threadIdx.x;
    if (tid >= N * HID) return;
    int n = tid >> 5, f = tid & 31;
    const float* row = z_emb + (size_t)z[n] * HID;
    float s = 0.f;
#pragma unroll
    for (int k = 0; k < HID; ++k) s += row[k] * W[k * HID + f];
    xw[tid] = s * dinv[n];
}

// ---------------- fused aggregation + next-layer xw GEMM ----------------
// One node per 32-lane half-wave (2 nodes/wave); f = lane&31.
// Predicated 8-deep unroll: 8 gathers in flight, no scalar tail.
// out[n][f] = tanh(dinv[n]*(sum_e ew_e*xws[src_e][f] + xws[n][f]) + b[f])
// MODE==0: xw_next[n][f'] = dinv[n]*sum_k out[k]*Wn[k][f']   (Wn 32x32)
// MODE==1: xw_next[n]     = dinv[n]*sum_k out[k]*Wn[k]       (Wn 32)
template <int MODE>
__global__ __launch_bounds__(256) void agg32f_kernel(
    const int* __restrict__ row_start, const int2* __restrict__ csr,
    const float* __restrict__ xw, const float* __restrict__ b,
    const float* __restrict__ dinv, const float* __restrict__ Wn,
    float* __restrict__ concat, int col_off, float* __restrict__ xw_next, int N) {
    int tid = blockIdx.x * blockDim.x + threadIdx.x;
    int n = tid >> 5;
    if (n >= N) return;
    int f = threadIdx.x & 31;
    int beg = row_start[n], end = row_start[n + 1];
    float s0 = 0.f, s1 = 0.f;
    for (int i = beg; i < end; i += 8) {
        float w[8];
        int idx[8];
#pragma unroll
        for (int j = 0; j < 8; ++j) {
            int ii = min(i + j, end - 1);   // clamp: duplicate last edge (same line, ~free)
            int2 v = csr[ii];
            idx[j] = v.x;
            w[j] = (i + j < end) ? __int_as_float(v.y) : 0.f;
        }
        float x[8];
#pragma unroll
        for (int j = 0; j < 8; ++j) x[j] = xw[(size_t)idx[j] * HID + f];
#pragma unroll
        for (int j = 0; j < 8; ++j) {
            if (j & 1) s1 += w[j] * x[j];
            else       s0 += w[j] * x[j];
        }
    }
    float s = s0 + s1;
    float di = dinv[n];
    float outv = tanhf(di * (s + xw[(size_t)n * HID + f]) + b[f]);
    concat[(size_t)n * DLAT + col_off + f] = outv;

    if (MODE == 0) {
        float p = 0.f;
#pragma unroll
        for (int k = 0; k < HID; ++k) {
            float ok = __shfl(outv, k, 32);  // lane k of this 32-lane segment
            p += ok * Wn[k * HID + f];
        }
        xw_next[(size_t)n * HID + f] = p * di;
    } else {
        float p = outv * Wn[f];
        p += __shfl_xor(p, 16);
        p += __shfl_xor(p, 8);
        p += __shfl_xor(p, 4);
        p += __shfl_xor(p, 2);
        p += __shfl_xor(p, 1);
        if (f == 0) xw_next[n] = p * di;
    }
}

// ---- fused: layer-4 agg + tanh + stable top-30 + CNN/MLP head (one block/graph) ----
__global__ __launch_bounds__(128) void topk_head_kernel(
    const int* __restrict__ row_start, const int2* __restrict__ csr,
    const float* __restrict__ xw4, const float* __restrict__ b4,
    const float* __restrict__ dinv, const float* __restrict__ concat,
    const float* __restrict__ Wc1, const float* __restrict__ bc1,
    const float* __restrict__ Wc2, const float* __restrict__ bc2,
    const float* __restrict__ Wl1, const float* __restrict__ bl1,
    const float* __restrict__ Wl2, const float* __restrict__ bl2,
    float* __restrict__ out) {
    int g = blockIdx.x;
    int tid = threadIdx.x;  // 128 threads
    __shared__ float v[NPG];
    __shared__ int tidx[TOPK];
    __shared__ float tval[TOPK];
    __shared__ float top[TOPK * DLAT];
    __shared__ float y1[16 * TOPK];
    __shared__ float y2[16 * 15];
    __shared__ float y3[352];
    __shared__ float r[128];

    // layer-4 aggregation for this graph's 100 nodes (xw4: 400 KB, L2-resident)
    if (tid < NPG) {
        int n = g * NPG + tid;
        int beg = row_start[n], end = row_start[n + 1];
        float s = 0.f;
        for (int i = beg; i < end; ++i) {
            int2 e = csr[i];
            s += __int_as_float(e.y) * xw4[e.x];
        }
        v[tid] = tanhf(dinv[n] * (s + xw4[n]) + b4[0]);
    }
    __syncthreads();
    // stable rank select (matches jnp.argsort(-v): lower index wins ties)
    if (tid < NPG) {
        float vi = v[tid];
        int cnt = 0;
#pragma unroll 4
        for (int j = 0; j < NPG; ++j) {
            float vj = v[j];
            cnt += (vj > vi) || (vj == vi && j < tid);
        }
        if (cnt < TOPK) {
            tidx[cnt] = g * NPG + tid;
            tval[cnt] = vi;
        }
    }
    __syncthreads();

    for (int idx = tid; idx < TOPK * DLAT; idx += 128) {
        int k = idx / DLAT, d = idx - k * DLAT;
        top[idx] = (d == 96) ? tval[k] : concat[(size_t)tidx[k] * DLAT + d];
    }
    __syncthreads();

    for (int idx = tid; idx < 16 * TOPK; idx += 128) {
        int c = idx / TOPK, k = idx % TOPK;
        float s = bc1[c];
        const float* w = Wc1 + c * DLAT;
        const float* t = top + k * DLAT;
#pragma unroll 4
        for (int d = 0; d < DLAT; ++d) s += t[d] * w[d];
        y1[c * TOPK + k] = fmaxf(s, 0.f);
    }
    __syncthreads();

    for (int idx = tid; idx < 16 * 15; idx += 128) {
        int c = idx / 15, j = idx % 15;
        y2[idx] = fmaxf(y1[c * TOPK + 2 * j], y1[c * TOPK + 2 * j + 1]);
    }
    __syncthreads();

    for (int idx = tid; idx < 352; idx += 128) {
        int o = idx / 11, t = idx % 11;
        float s = bc2[o];
#pragma unroll
        for (int i = 0; i < 16; ++i) {
#pragma unroll
            for (int k = 0; k < 5; ++k)
                s += Wc2[(o * 16 + i) * 5 + k] * y2[i * 15 + t + k];
        }
        y3[idx] = fmaxf(s, 0.f);
    }
    __syncthreads();

    {
        float s = bl1[tid];
        for (int d = 0; d < 352; ++d) s += y3[d] * Wl1[d * 128 + tid];
        r[tid] = fmaxf(s, 0.f) * Wl2[tid];
    }
    __syncthreads();
    if (tid < 64) r[tid] += r[tid + 64];
    __syncthreads();
    if (tid == 0) {
        float s = 0.f;
        for (int j = 0; j < 64; ++j) s += r[j];
        out[g] = s + bl2[0];
    }
}

// ---------------- launch ----------------

extern "C" void kernel_launch(void* const* d_in, const int* in_sizes, int n_in,
                              void* d_out, int out_size, void* d_ws, size_t ws_size,
                              hipStream_t stream) {
    const int* z = (const int*)d_in[0];
    const int* ei = (const int*)d_in[1];
    const float* ew = (const float*)d_in[3];
    const float* z_emb = (const float*)d_in[4];
    const float* Wg[4] = {(const float*)d_in[5], (const float*)d_in[7],
                          (const float*)d_in[9], (const float*)d_in[11]};
    const float* bg[4] = {(const float*)d_in[6], (const float*)d_in[8],
                          (const float*)d_in[10], (const float*)d_in[12]};
    const float* Wc1 = (const float*)d_in[13];
    const float* bc1 = (const float*)d_in[14];
    const float* Wc2 = (const float*)d_in[15];
    const float* bc2 = (const float*)d_in[16];
    const float* Wl1 = (const float*)d_in[17];
    const float* bl1 = (const float*)d_in[18];
    const float* Wl2 = (const float*)d_in[19];
    const float* bl2 = (const float*)d_in[20];
    float* out = (float*)d_out;

    const int N = in_sizes[0];
    const int E = in_sizes[1] / 2;
    const int G = out_size;  // 1000 graphs
    const int* src = ei;
    const int* dst = ei + E;

    auto cdiv = [](long long a, long long b) { return (int)((a + b - 1) / b); };
    const int NB = cdiv(E, EPB);
    const int NBKT = cdiv(N, BKT_NODES);

    // workspace layout (8B-aligned arrays first)
    char* ws = (char*)d_ws;
    int2* bedge = (int2*)ws;                  ws += sizeof(int2) * (size_t)E;
    int2* csr = (int2*)ws;                    ws += sizeof(int2) * (size_t)E;
    int* blockhist = (int*)ws;                ws += sizeof(int) * (size_t)NB * MAXBKT;
    int* bucket_start = (int*)ws;             ws += sizeof(int) * (MAXBKT + 1);
    int* row_start = (int*)ws;                ws += sizeof(int) * (N + 1);
    float* dinv = (float*)ws;                 ws += sizeof(float) * N;
    float* xw_a = (float*)ws;                 ws += sizeof(float) * (size_t)N * HID;
    float* concat = (float*)ws;               ws += sizeof(float) * (size_t)N * DLAT;
    float* xw4 = (float*)ws;                  ws += sizeof(float) * N;
    // xw ping-pong: B-buffer aliases bedge (dead after sortlocal; N*128B == E*8B)
    float* xw_b = (float*)bedge;

    const int B = 256;

    // deterministic two-level sort: bucket partition + per-bucket counting sort (+dinv)
    binA_kernel<<<NB, B, 0, stream>>>(dst, blockhist, E);
    binscan_kernel<<<1, MAXBKT, 0, stream>>>(blockhist, bucket_start, NB);
    binB_kernel<<<NB, B, 0, stream>>>(src, dst, ew, blockhist, bucket_start, bedge, E);
    sortlocal_kernel<<<NBKT, BKT_NODES, 0, stream>>>(bedge, bucket_start, csr, row_start,
                                                     dinv, N, E);

    // layer-1 xw, then fused agg+next-xw chain (1 node per 32-lane half)
    xw1_kernel<<<cdiv((long long)N * HID, B), B, 0, stream>>>(z, z_emb, Wg[0], dinv, xw_a, N);
    const int AGGB = cdiv((long long)N * 32, B);
    agg32f_kernel<0><<<AGGB, B, 0, stream>>>(row_start, csr, xw_a, bg[0], dinv, Wg[1],
                                             concat, 0, xw_b, N);
    agg32f_kernel<0><<<AGGB, B, 0, stream>>>(row_start, csr, xw_b, bg[1], dinv, Wg[2],
                                             concat, 32, xw_a, N);
    agg32f_kernel<1><<<AGGB, B, 0, stream>>>(row_start, csr, xw_a, bg[2], dinv, Wg[3],
                                             concat, 64, xw4, N);

    // fused layer-4 agg + tanh + top-30 + head
    topk_head_kernel<<<G, 128, 0, stream>>>(row_start, csr, xw4, bg[3], dinv, concat,
                                            Wc1, bc1, Wc2, bc2, Wl1, bl1, Wl2, bl2, out);
}

// Round 8
// 423.124 us; speedup vs baseline: 3.4093x; 1.0056x over previous
//
#include <hip/hip_runtime.h>

#define HID 32
#define DLAT 97
#define NPG 100
#define TOPK 30
#define BKT_NODES 256   // nodes per bucket (bucket = dst >> 8)
#define MAXBKT 512      // >= ceil(N/256); N=100000 -> 391
#define EPB 4096        // edges per binning block

// ---------------- binning: partition edges by dst bucket ----------------
// Round-8 structure: no blockhist, no serial column scan. Per-bucket totals via
// LDS-hist + global atomics; per-block placement via atomic range reservation.
// Within-bucket edge order is nondeterministic (sum order only -> ~1e-7 jitter).

__global__ void binA_kernel(const int* __restrict__ dst, int* __restrict__ bucket_cnt, int E) {
    __shared__ int hist[MAXBKT];
    for (int t = threadIdx.x; t < MAXBKT; t += blockDim.x) hist[t] = 0;
    __syncthreads();
    int base = blockIdx.x * EPB;
    int lim = min(E, base + EPB);
    for (int e = base + threadIdx.x; e < lim; e += blockDim.x)
        atomicAdd(&hist[dst[e] >> 8], 1);
    __syncthreads();
    for (int t = threadIdx.x; t < MAXBKT; t += blockDim.x) {
        int v = hist[t];
        if (v) atomicAdd(&bucket_cnt[t], v);
    }
}

// single small block: exclusive scan of bucket_cnt[512] -> bucket_start, cursor
__global__ __launch_bounds__(MAXBKT) void bscan_kernel(const int* __restrict__ bucket_cnt,
                                                       int* __restrict__ bucket_start,
                                                       int* __restrict__ cursor) {
    __shared__ int sh[MAXBKT];
    int t = threadIdx.x;
    int v = bucket_cnt[t];
    sh[t] = v;
    __syncthreads();
    for (int off = 1; off < MAXBKT; off <<= 1) {
        int tv = (t >= off) ? sh[t - off] : 0;
        __syncthreads();
        sh[t] += tv;
        __syncthreads();
    }
    int excl = sh[t] - v;
    bucket_start[t] = excl;
    cursor[t] = excl;
    if (t == MAXBKT - 1) bucket_start[MAXBKT] = sh[t];  // = E
}

// LDS hist -> reserve contiguous range per (block,bucket) -> scatter
__global__ void binB_kernel(const int* __restrict__ src, const int* __restrict__ dst,
                            const float* __restrict__ ew, int* __restrict__ cursor,
                            int2* __restrict__ bedge, int E) {
    __shared__ int hist[MAXBKT];
    __shared__ int lcur[MAXBKT];
    for (int t = threadIdx.x; t < MAXBKT; t += blockDim.x) hist[t] = 0;
    __syncthreads();
    int base = blockIdx.x * EPB;
    int lim = min(E, base + EPB);
    for (int e = base + threadIdx.x; e < lim; e += blockDim.x)
        atomicAdd(&hist[dst[e] >> 8], 1);
    __syncthreads();
    for (int t = threadIdx.x; t < MAXBKT; t += blockDim.x) {
        int v = hist[t];
        lcur[t] = v ? atomicAdd(&cursor[t], v) : 0;
    }
    __syncthreads();
    for (int e = base + threadIdx.x; e < lim; e += blockDim.x) {
        int d = dst[e];
        int slot = atomicAdd(&lcur[d >> 8], 1);
        bedge[slot] = make_int2(src[e] | ((d & 255) << 20), __float_as_int(ew[e]));
    }
}

// per-bucket counting sort -> dst-sorted CSR {src, ew} + row_start + dinv (fused)
__global__ __launch_bounds__(BKT_NODES) void sortlocal_kernel(
    const int2* __restrict__ bedge, const int* __restrict__ bucket_start,
    int2* __restrict__ csr, int* __restrict__ row_start, float* __restrict__ dinv,
    int N, int E) {
    __shared__ int cnt[BKT_NODES];
    __shared__ float facc[BKT_NODES];
    __shared__ int sh[BKT_NODES];
    __shared__ int lcur[BKT_NODES];
    int b = blockIdx.x;
    int beg = bucket_start[b], end = bucket_start[b + 1];
    int t = threadIdx.x;
    cnt[t] = 0;
    facc[t] = 0.f;
    __syncthreads();
    for (int i = beg + t; i < end; i += BKT_NODES) {
        int2 e = bedge[i];
        int loc = e.x >> 20;
        atomicAdd(&cnt[loc], 1);
        atomicAdd(&facc[loc], __int_as_float(e.y));
    }
    __syncthreads();
    int n = b * BKT_NODES + t;
    if (n < N) dinv[n] = 1.0f / sqrtf(1.0f + facc[t]);  // deg = 1 + sum(ew)
    int v = cnt[t];
    sh[t] = v;
    __syncthreads();
    for (int off = 1; off < BKT_NODES; off <<= 1) {
        int tv = (t >= off) ? sh[t - off] : 0;
        __syncthreads();
        sh[t] += tv;
        __syncthreads();
    }
    int excl = sh[t] - v;
    lcur[t] = excl;
    if (n < N) row_start[n] = beg + excl;
    if (b == 0 && t == 0) row_start[N] = E;
    __syncthreads();
    for (int i = beg + t; i < end; i += BKT_NODES) {
        int2 e = bedge[i];
        int slot = atomicAdd(&lcur[e.x >> 20], 1);
        csr[beg + slot] = make_int2(e.x & 0xFFFFF, e.y);
    }
}

// layer 1: xw[n][f] = dinv[n] * dot(z_emb[z[n]], W[:,f])
__global__ void xw1_kernel(const int* __restrict__ z, const float* __restrict__ z_emb,
                           const float* __restrict__ W, const float* __restrict__ dinv,
                           float* __restrict__ xw, int N) {
    int tid = blockIdx.x * blockDim.x + threadIdx.x;
    if (tid >= N * HID) return;
    int n = tid >> 5, f = tid & 31;
    const float* row = z_emb + (size_t)z[n] * HID;
    float s = 0.f;
#pragma unroll
    for (int k = 0; k < HID; ++k) s += row[k] * W[k * HID + f];
    xw[tid] = s * dinv[n];
}

// ---------------- fused aggregation + next-layer xw GEMM ----------------
// One node per 32-lane half-wave; predicated 8-deep unrolled gathers.
template <int MODE>
__global__ __launch_bounds__(256) void agg32f_kernel(
    const int* __restrict__ row_start, const int2* __restrict__ csr,
    const float* __restrict__ xw, const float* __restrict__ b,
    const float* __restrict__ dinv, const float* __restrict__ Wn,
    float* __restrict__ concat, int col_off, float* __restrict__ xw_next, int N) {
    int tid = blockIdx.x * blockDim.x + threadIdx.x;
    int n = tid >> 5;
    if (n >= N) return;
    int f = threadIdx.x & 31;
    int beg = row_start[n], end = row_start[n + 1];
    float s0 = 0.f, s1 = 0.f;
    for (int i = beg; i < end; i += 8) {
        float w[8];
        int idx[8];
#pragma unroll
        for (int j = 0; j < 8; ++j) {
            int ii = min(i + j, end - 1);   // clamp: duplicate last edge, weight 0
            int2 v = csr[ii];
            idx[j] = v.x;
            w[j] = (i + j < end) ? __int_as_float(v.y) : 0.f;
        }
        float x[8];
#pragma unroll
        for (int j = 0; j < 8; ++j) x[j] = xw[(size_t)idx[j] * HID + f];
#pragma unroll
        for (int j = 0; j < 8; ++j) {
            if (j & 1) s1 += w[j] * x[j];
            else       s0 += w[j] * x[j];
        }
    }
    float s = s0 + s1;
    float di = dinv[n];
    float outv = tanhf(di * (s + xw[(size_t)n * HID + f]) + b[f]);
    concat[(size_t)n * DLAT + col_off + f] = outv;

    if (MODE == 0) {
        float p = 0.f;
#pragma unroll
        for (int k = 0; k < HID; ++k) {
            float ok = __shfl(outv, k, 32);
            p += ok * Wn[k * HID + f];
        }
        xw_next[(size_t)n * HID + f] = p * di;
    } else {
        float p = outv * Wn[f];
        p += __shfl_xor(p, 16);
        p += __shfl_xor(p, 8);
        p += __shfl_xor(p, 4);
        p += __shfl_xor(p, 2);
        p += __shfl_xor(p, 1);
        if (f == 0) xw_next[n] = p * di;
    }
}

// ---- fused: layer-4 agg + tanh + stable top-30 + CNN/MLP head (one block/graph) ----
__global__ __launch_bounds__(128) void topk_head_kernel(
    const int* __restrict__ row_start, const int2* __restrict__ csr,
    const float* __restrict__ xw4, const float* __restrict__ b4,
    const float* __restrict__ dinv, const float* __restrict__ concat,
    const float* __restrict__ Wc1, const float* __restrict__ bc1,
    const float* __restrict__ Wc2, const float* __restrict__ bc2,
    const float* __restrict__ Wl1, const float* __restrict__ bl1,
    const float* __restrict__ Wl2, const float* __restrict__ bl2,
    float* __restrict__ out) {
    int g = blockIdx.x;
    int tid = threadIdx.x;  // 128 threads
    __shared__ float v[NPG];
    __shared__ int tidx[TOPK];
    __shared__ float tval[TOPK];
    __shared__ float top[TOPK * DLAT];
    __shared__ float y1[16 * TOPK];
    __shared__ float y2[16 * 15];
    __shared__ float y3[352];
    __shared__ float r[128];

    if (tid < NPG) {
        int n = g * NPG + tid;
        int beg = row_start[n], end = row_start[n + 1];
        float s = 0.f;
        for (int i = beg; i < end; ++i) {
            int2 e = csr[i];
            s += __int_as_float(e.y) * xw4[e.x];
        }
        v[tid] = tanhf(dinv[n] * (s + xw4[n]) + b4[0]);
    }
    __syncthreads();
    // stable rank select (matches jnp.argsort(-v): lower index wins ties)
    if (tid < NPG) {
        float vi = v[tid];
        int cnt = 0;
#pragma unroll 4
        for (int j = 0; j < NPG; ++j) {
            float vj = v[j];
            cnt += (vj > vi) || (vj == vi && j < tid);
        }
        if (cnt < TOPK) {
            tidx[cnt] = g * NPG + tid;
            tval[cnt] = vi;
        }
    }
    __syncthreads();

    for (int idx = tid; idx < TOPK * DLAT; idx += 128) {
        int k = idx / DLAT, d = idx - k * DLAT;
        top[idx] = (d == 96) ? tval[k] : concat[(size_t)tidx[k] * DLAT + d];
    }
    __syncthreads();

    for (int idx = tid; idx < 16 * TOPK; idx += 128) {
        int c = idx / TOPK, k = idx % TOPK;
        float s = bc1[c];
        const float* w = Wc1 + c * DLAT;
        const float* t = top + k * DLAT;
#pragma unroll 4
        for (int d = 0; d < DLAT; ++d) s += t[d] * w[d];
        y1[c * TOPK + k] = fmaxf(s, 0.f);
    }
    __syncthreads();

    for (int idx = tid; idx < 16 * 15; idx += 128) {
        int c = idx / 15, j = idx % 15;
        y2[idx] = fmaxf(y1[c * TOPK + 2 * j], y1[c * TOPK + 2 * j + 1]);
    }
    __syncthreads();

    for (int idx = tid; idx < 352; idx += 128) {
        int o = idx / 11, t = idx % 11;
        float s = bc2[o];
#pragma unroll
        for (int i = 0; i < 16; ++i) {
#pragma unroll
            for (int k = 0; k < 5; ++k)
                s += Wc2[(o * 16 + i) * 5 + k] * y2[i * 15 + t + k];
        }
        y3[idx] = fmaxf(s, 0.f);
    }
    __syncthreads();

    {
        float s = bl1[tid];
        for (int d = 0; d < 352; ++d) s += y3[d] * Wl1[d * 128 + tid];
        r[tid] = fmaxf(s, 0.f) * Wl2[tid];
    }
    __syncthreads();
    if (tid < 64) r[tid] += r[tid + 64];
    __syncthreads();
    if (tid == 0) {
        float s = 0.f;
        for (int j = 0; j < 64; ++j) s += r[j];
        out[g] = s + bl2[0];
    }
}

// ---------------- launch ----------------

extern "C" void kernel_launch(void* const* d_in, const int* in_sizes, int n_in,
                              void* d_out, int out_size, void* d_ws, size_t ws_size,
                              hipStream_t stream) {
    const int* z = (const int*)d_in[0];
    const int* ei = (const int*)d_in[1];
    const float* ew = (const float*)d_in[3];
    const float* z_emb = (const float*)d_in[4];
    const float* Wg[4] = {(const float*)d_in[5], (const float*)d_in[7],
                          (const float*)d_in[9], (const float*)d_in[11]};
    const float* bg[4] = {(const float*)d_in[6], (const float*)d_in[8],
                          (const float*)d_in[10], (const float*)d_in[12]};
    const float* Wc1 = (const float*)d_in[13];
    const float* bc1 = (const float*)d_in[14];
    const float* Wc2 = (const float*)d_in[15];
    const float* bc2 = (const float*)d_in[16];
    const float* Wl1 = (const float*)d_in[17];
    const float* bl1 = (const float*)d_in[18];
    const float* Wl2 = (const float*)d_in[19];
    const float* bl2 = (const float*)d_in[20];
    float* out = (float*)d_out;

    const int N = in_sizes[0];
    const int E = in_sizes[1] / 2;
    const int G = out_size;  // 1000 graphs
    const int* src = ei;
    const int* dst = ei + E;

    auto cdiv = [](long long a, long long b) { return (int)((a + b - 1) / b); };
    const int NB = cdiv(E, EPB);
    const int NBKT = cdiv(N, BKT_NODES);

    // workspace layout (8B-aligned arrays first)
    char* ws = (char*)d_ws;
    int2* bedge = (int2*)ws;                  ws += sizeof(int2) * (size_t)E;
    int2* csr = (int2*)ws;                    ws += sizeof(int2) * (size_t)E;
    int* bucket_cnt = (int*)ws;               ws += sizeof(int) * MAXBKT;
    int* bucket_start = (int*)ws;             ws += sizeof(int) * (MAXBKT + 1);
    int* cursor = (int*)ws;                   ws += sizeof(int) * MAXBKT;
    int* row_start = (int*)ws;                ws += sizeof(int) * (N + 1);
    float* dinv = (float*)ws;                 ws += sizeof(float) * N;
    float* xw_a = (float*)ws;                 ws += sizeof(float) * (size_t)N * HID;
    float* concat = (float*)ws;               ws += sizeof(float) * (size_t)N * DLAT;
    float* xw4 = (float*)ws;                  ws += sizeof(float) * N;
    // xw ping-pong: B-buffer aliases bedge (dead after sortlocal; N*128B == E*8B)
    float* xw_b = (float*)bedge;

    const int B = 256;

    // bucket partition via atomic range reservation + per-bucket counting sort
    hipMemsetAsync(bucket_cnt, 0, sizeof(int) * MAXBKT, stream);
    binA_kernel<<<NB, B, 0, stream>>>(dst, bucket_cnt, E);
    bscan_kernel<<<1, MAXBKT, 0, stream>>>(bucket_cnt, bucket_start, cursor);
    binB_kernel<<<NB, B, 0, stream>>>(src, dst, ew, cursor, bedge, E);
    sortlocal_kernel<<<NBKT, BKT_NODES, 0, stream>>>(bedge, bucket_start, csr, row_start,
                                                     dinv, N, E);

    // layer-1 xw, then fused agg+next-xw chain (1 node per 32-lane half)
    xw1_kernel<<<cdiv((long long)N * HID, B), B, 0, stream>>>(z, z_emb, Wg[0], dinv, xw_a, N);
    const int AGGB = cdiv((long long)N * 32, B);
    agg32f_kernel<0><<<AGGB, B, 0, stream>>>(row_start, csr, xw_a, bg[0], dinv, Wg[1],
                                             concat, 0, xw_b, N);
    agg32f_kernel<0><<<AGGB, B, 0, stream>>>(row_start, csr, xw_b, bg[1], dinv, Wg[2],
                                             concat, 32, xw_a, N);
    agg32f_kernel<1><<<AGGB, B, 0, stream>>>(row_start, csr, xw_a, bg[2], dinv, Wg[3],
                                             concat, 64, xw4, N);

    // fused layer-4 agg + tanh + top-30 + head
    topk_head_kernel<<<G, 128, 0, stream>>>(row_start, csr, xw4, bg[3], dinv, concat,
                                            Wc1, bc1, Wc2, bc2, Wl1, bl1, Wl2, bl2, out);
}

// Round 9
// 417.487 us; speedup vs baseline: 3.4554x; 1.0135x over previous
//
#include <hip/hip_runtime.h>

#define HID 32
#define DLAT 97
#define NPG 100
#define TOPK 30
#define BKT_NODES 128   // nodes per bucket (bucket = dst >> 7)
#define BKT_SHIFT 7
#define MAXBKT 1024     // >= ceil(N/128); N=100000 -> 782
#define CAP 3072        // max edges per bucket held in LDS (exp 2046, sigma 45)
#define CHUNK 8192      // edges per binning block

// ---------------- binning: partition edges by dst bucket ----------------

__global__ __launch_bounds__(256) void binA_kernel(const int* __restrict__ dst,
                                                   int* __restrict__ bucket_cnt, int E) {
    __shared__ int hist[MAXBKT];
    for (int t = threadIdx.x; t < MAXBKT; t += 256) hist[t] = 0;
    __syncthreads();
    int base = blockIdx.x * CHUNK;
    int lim = min(E, base + CHUNK);
    for (int e = base + threadIdx.x; e < lim; e += 256)
        atomicAdd(&hist[dst[e] >> BKT_SHIFT], 1);
    __syncthreads();
    for (int t = threadIdx.x; t < MAXBKT; t += 256) {
        int v = hist[t];
        if (v) atomicAdd(&bucket_cnt[t], v);
    }
}

// single block: exclusive scan of bucket_cnt[1024] -> bucket_start, cursor
__global__ __launch_bounds__(MAXBKT) void bscan_kernel(const int* __restrict__ bucket_cnt,
                                                       int* __restrict__ bucket_start,
                                                       int* __restrict__ cursor) {
    __shared__ int sh[MAXBKT];
    int t = threadIdx.x;
    int v = bucket_cnt[t];
    sh[t] = v;
    __syncthreads();
    for (int off = 1; off < MAXBKT; off <<= 1) {
        int tv = (t >= off) ? sh[t - off] : 0;
        __syncthreads();
        sh[t] += tv;
        __syncthreads();
    }
    int excl = sh[t] - v;
    bucket_start[t] = excl;
    cursor[t] = excl;
    if (t == MAXBKT - 1) bucket_start[MAXBKT] = sh[t];  // = E
}

// LDS dst-cache + hist -> reserve ranges -> scatter (dst read ONCE from global)
__global__ __launch_bounds__(256) void binB_kernel(const int* __restrict__ src,
                                                   const int* __restrict__ dst,
                                                   const float* __restrict__ ew,
                                                   int* __restrict__ cursor,
                                                   int2* __restrict__ bedge, int E) {
    __shared__ int hist[MAXBKT];
    __shared__ int lcur[MAXBKT];
    __shared__ int dcache[CHUNK];
    for (int t = threadIdx.x; t < MAXBKT; t += 256) hist[t] = 0;
    __syncthreads();
    int base = blockIdx.x * CHUNK;
    int M = min(E - base, CHUNK);
    for (int i = threadIdx.x; i < M; i += 256) {
        int d = dst[base + i];
        dcache[i] = d;
        atomicAdd(&hist[d >> BKT_SHIFT], 1);
    }
    __syncthreads();
    for (int t = threadIdx.x; t < MAXBKT; t += 256) {
        int v = hist[t];
        lcur[t] = v ? atomicAdd(&cursor[t], v) : 0;
    }
    __syncthreads();
    for (int i = threadIdx.x; i < M; i += 256) {
        int d = dcache[i];
        int slot = atomicAdd(&lcur[d >> BKT_SHIFT], 1);
        bedge[slot] = make_int2(src[base + i] | ((d & (BKT_NODES - 1)) << 20),
                                __float_as_int(ew[base + i]));
    }
}

// per-bucket counting sort, LDS-resident: one global read of bedge, coalesced-ish
// csr scatter into a 24KB L2-hot window, sequential (atomic-free) dinv.
__global__ __launch_bounds__(256) void sortlocal_kernel(
    const int2* __restrict__ bedge, const int* __restrict__ bucket_start,
    int2* __restrict__ csr, int* __restrict__ row_start, float* __restrict__ dinv,
    int N, int E) {
    __shared__ int2 LDSe[CAP];          // 24 KB
    __shared__ int cnt[BKT_NODES];
    __shared__ int sh[BKT_NODES];
    __shared__ int lcur[BKT_NODES];
    __shared__ float facc[BKT_NODES];
    int b = blockIdx.x, t = threadIdx.x;
    int beg = bucket_start[b], end = bucket_start[b + 1], M = end - beg;
    if (t < BKT_NODES) { cnt[t] = 0; facc[t] = 0.f; }
    __syncthreads();
    int n = b * BKT_NODES + t;
    if (M <= CAP) {
        for (int i = t; i < M; i += 256) {
            int2 e = bedge[beg + i];
            LDSe[i] = e;
            atomicAdd(&cnt[(e.x >> 20) & (BKT_NODES - 1)], 1);
        }
        __syncthreads();
        int v = 0;
        if (t < BKT_NODES) { v = cnt[t]; sh[t] = v; }
        __syncthreads();
        for (int off = 1; off < BKT_NODES; off <<= 1) {
            int tv = (t >= off && t < BKT_NODES) ? sh[t - off] : 0;
            __syncthreads();
            if (t < BKT_NODES) sh[t] += tv;
            __syncthreads();
        }
        int excl = 0;
        if (t < BKT_NODES) {
            excl = sh[t] - v;
            lcur[t] = excl;
            if (n < N) row_start[n] = beg + excl;
        }
        if (b == 0 && t == 0) row_start[N] = E;
        __syncthreads();
        for (int i = t; i < M; i += 256) {
            int2 e = LDSe[i];
            int slot = atomicAdd(&lcur[(e.x >> 20) & (BKT_NODES - 1)], 1);
            csr[beg + slot] = make_int2(e.x & 0xFFFFF, e.y);
        }
        __syncthreads();  // drains this block's global writes (vmcnt(0) before barrier)
        if (t < BKT_NODES && n < N) {
            float s = 1.f;
            int s0 = beg + excl;
            for (int i = 0; i < v; ++i) s += __int_as_float(csr[s0 + i].y);
            dinv[n] = 1.f / sqrtf(s);
        }
    } else {
        // fallback (not expected for random edges): two-pass from global
        for (int i = beg + t; i < end; i += 256) {
            int2 e = bedge[i];
            int loc = (e.x >> 20) & (BKT_NODES - 1);
            atomicAdd(&cnt[loc], 1);
            atomicAdd(&facc[loc], __int_as_float(e.y));
        }
        __syncthreads();
        int v = 0;
        if (t < BKT_NODES) { v = cnt[t]; sh[t] = v; }
        __syncthreads();
        for (int off = 1; off < BKT_NODES; off <<= 1) {
            int tv = (t >= off && t < BKT_NODES) ? sh[t - off] : 0;
            __syncthreads();
            if (t < BKT_NODES) sh[t] += tv;
            __syncthreads();
        }
        if (t < BKT_NODES) {
            int excl = sh[t] - v;
            lcur[t] = excl;
            if (n < N) {
                row_start[n] = beg + excl;
                dinv[n] = 1.f / sqrtf(1.f + facc[t]);
            }
        }
        if (b == 0 && t == 0) row_start[N] = E;
        __syncthreads();
        for (int i = beg + t; i < end; i += 256) {
            int2 e = bedge[i];
            int slot = atomicAdd(&lcur[(e.x >> 20) & (BKT_NODES - 1)], 1);
            csr[beg + slot] = make_int2(e.x & 0xFFFFF, e.y);
        }
    }
}

// layer 1: xw[n][f] = dinv[n] * dot(z_emb[z[n]], W[:,f])
__global__ void xw1_kernel(const int* __restrict__ z, const float* __restrict__ z_emb,
                           const float* __restrict__ W, const float* __restrict__ dinv,
                           float* __restrict__ xw, int N) {
    int tid = blockIdx.x * blockDim.x + threadIdx.x;
    if (tid >= N * HID) return;
    int n = tid >> 5, f = tid & 31;
    const float* row = z_emb + (size_t)z[n] * HID;
    float s = 0.f;
#pragma unroll
    for (int k = 0; k < HID; ++k) s += row[k] * W[k * HID + f];
    xw[tid] = s * dinv[n];
}

// ---------------- fused aggregation + next-layer xw GEMM ----------------
// One node per 32-lane half-wave; predicated 8-deep unrolled gathers.
template <int MODE>
__global__ __launch_bounds__(256) void agg32f_kernel(
    const int* __restrict__ row_start, const int2* __restrict__ csr,
    const float* __restrict__ xw, const float* __restrict__ b,
    const float* __restrict__ dinv, const float* __restrict__ Wn,
    float* __restrict__ concat, int col_off, float* __restrict__ xw_next, int N) {
    int tid = blockIdx.x * blockDim.x + threadIdx.x;
    int n = tid >> 5;
    if (n >= N) return;
    int f = threadIdx.x & 31;
    int beg = row_start[n], end = row_start[n + 1];
    float s0 = 0.f, s1 = 0.f;
    for (int i = beg; i < end; i += 8) {
        float w[8];
        int idx[8];
#pragma unroll
        for (int j = 0; j < 8; ++j) {
            int ii = min(i + j, end - 1);   // clamp: duplicate last edge, weight 0
            int2 v = csr[ii];
            idx[j] = v.x;
            w[j] = (i + j < end) ? __int_as_float(v.y) : 0.f;
        }
        float x[8];
#pragma unroll
        for (int j = 0; j < 8; ++j) x[j] = xw[(size_t)idx[j] * HID + f];
#pragma unroll
        for (int j = 0; j < 8; ++j) {
            if (j & 1) s1 += w[j] * x[j];
            else       s0 += w[j] * x[j];
        }
    }
    float s = s0 + s1;
    float di = dinv[n];
    float outv = tanhf(di * (s + xw[(size_t)n * HID + f]) + b[f]);
    concat[(size_t)n * DLAT + col_off + f] = outv;

    if (MODE == 0) {
        float p = 0.f;
#pragma unroll
        for (int k = 0; k < HID; ++k) {
            float ok = __shfl(outv, k, 32);
            p += ok * Wn[k * HID + f];
        }
        xw_next[(size_t)n * HID + f] = p * di;
    } else {
        float p = outv * Wn[f];
        p += __shfl_xor(p, 16);
        p += __shfl_xor(p, 8);
        p += __shfl_xor(p, 4);
        p += __shfl_xor(p, 2);
        p += __shfl_xor(p, 1);
        if (f == 0) xw_next[n] = p * di;
    }
}

// ---- fused: layer-4 agg + tanh + stable top-30 + CNN/MLP head (one block/graph) ----
__global__ __launch_bounds__(128) void topk_head_kernel(
    const int* __restrict__ row_start, const int2* __restrict__ csr,
    const float* __restrict__ xw4, const float* __restrict__ b4,
    const float* __restrict__ dinv, const float* __restrict__ concat,
    const float* __restrict__ Wc1, const float* __restrict__ bc1,
    const float* __restrict__ Wc2, const float* __restrict__ bc2,
    const float* __restrict__ Wl1, const float* __restrict__ bl1,
    const float* __restrict__ Wl2, const float* __restrict__ bl2,
    float* __restrict__ out) {
    int g = blockIdx.x;
    int tid = threadIdx.x;  // 128 threads
    __shared__ float v[NPG];
    __shared__ int tidx[TOPK];
    __shared__ float tval[TOPK];
    __shared__ float top[TOPK * DLAT];
    __shared__ float y1[16 * TOPK];
    __shared__ float y2[16 * 15];
    __shared__ float y3[352];
    __shared__ float r[128];

    if (tid < NPG) {
        int n = g * NPG + tid;
        int beg = row_start[n], end = row_start[n + 1];
        float s = 0.f;
        for (int i = beg; i < end; ++i) {
            int2 e = csr[i];
            s += __int_as_float(e.y) * xw4[e.x];
        }
        v[tid] = tanhf(dinv[n] * (s + xw4[n]) + b4[0]);
    }
    __syncthreads();
    // stable rank select (matches jnp.argsort(-v): lower index wins ties)
    if (tid < NPG) {
        float vi = v[tid];
        int cnt = 0;
#pragma unroll 4
        for (int j = 0; j < NPG; ++j) {
            float vj = v[j];
            cnt += (vj > vi) || (vj == vi && j < tid);
        }
        if (cnt < TOPK) {
            tidx[cnt] = g * NPG + tid;
            tval[cnt] = vi;
        }
    }
    __syncthreads();

    for (int idx = tid; idx < TOPK * DLAT; idx += 128) {
        int k = idx / DLAT, d = idx - k * DLAT;
        top[idx] = (d == 96) ? tval[k] : concat[(size_t)tidx[k] * DLAT + d];
    }
    __syncthreads();

    for (int idx = tid; idx < 16 * TOPK; idx += 128) {
        int c = idx / TOPK, k = idx % TOPK;
        float s = bc1[c];
        const float* w = Wc1 + c * DLAT;
        const float* t = top + k * DLAT;
#pragma unroll 4
        for (int d = 0; d < DLAT; ++d) s += t[d] * w[d];
        y1[c * TOPK + k] = fmaxf(s, 0.f);
    }
    __syncthreads();

    for (int idx = tid; idx < 16 * 15; idx += 128) {
        int c = idx / 15, j = idx % 15;
        y2[idx] = fmaxf(y1[c * TOPK + 2 * j], y1[c * TOPK + 2 * j + 1]);
    }
    __syncthreads();

    for (int idx = tid; idx < 352; idx += 128) {
        int o = idx / 11, t = idx % 11;
        float s = bc2[o];
#pragma unroll
        for (int i = 0; i < 16; ++i) {
#pragma unroll
            for (int k = 0; k < 5; ++k)
                s += Wc2[(o * 16 + i) * 5 + k] * y2[i * 15 + t + k];
        }
        y3[idx] = fmaxf(s, 0.f);
    }
    __syncthreads();

    {
        float s = bl1[tid];
        for (int d = 0; d < 352; ++d) s += y3[d] * Wl1[d * 128 + tid];
        r[tid] = fmaxf(s, 0.f) * Wl2[tid];
    }
    __syncthreads();
    if (tid < 64) r[tid] += r[tid + 64];
    __syncthreads();
    if (tid == 0) {
        float s = 0.f;
        for (int j = 0; j < 64; ++j) s += r[j];
        out[g] = s + bl2[0];
    }
}

// ---------------- launch ----------------

extern "C" void kernel_launch(void* const* d_in, const int* in_sizes, int n_in,
                              void* d_out, int out_size, void* d_ws, size_t ws_size,
                              hipStream_t stream) {
    const int* z = (const int*)d_in[0];
    const int* ei = (const int*)d_in[1];
    const float* ew = (const float*)d_in[3];
    const float* z_emb = (const float*)d_in[4];
    const float* Wg[4] = {(const float*)d_in[5], (const float*)d_in[7],
                          (const float*)d_in[9], (const float*)d_in[11]};
    const float* bg[4] = {(const float*)d_in[6], (const float*)d_in[8],
                          (const float*)d_in[10], (const float*)d_in[12]};
    const float* Wc1 = (const float*)d_in[13];
    const float* bc1 = (const float*)d_in[14];
    const float* Wc2 = (const float*)d_in[15];
    const float* bc2 = (const float*)d_in[16];
    const float* Wl1 = (const float*)d_in[17];
    const float* bl1 = (const float*)d_in[18];
    const float* Wl2 = (const float*)d_in[19];
    const float* bl2 = (const float*)d_in[20];
    float* out = (float*)d_out;

    const int N = in_sizes[0];
    const int E = in_sizes[1] / 2;
    const int G = out_size;  // 1000 graphs
    const int* src = ei;
    const int* dst = ei + E;

    auto cdiv = [](long long a, long long b) { return (int)((a + b - 1) / b); };
    const int NB = cdiv(E, CHUNK);
    const int NBKT = cdiv(N, BKT_NODES);

    // workspace layout (8B-aligned arrays first)
    char* ws = (char*)d_ws;
    int2* bedge = (int2*)ws;                  ws += sizeof(int2) * (size_t)E;
    int2* csr = (int2*)ws;                    ws += sizeof(int2) * (size_t)E;
    int* bucket_cnt = (int*)ws;               ws += sizeof(int) * MAXBKT;
    int* bucket_start = (int*)ws;             ws += sizeof(int) * (MAXBKT + 1);
    int* cursor = (int*)ws;                   ws += sizeof(int) * MAXBKT;
    int* row_start = (int*)ws;                ws += sizeof(int) * (N + 1);
    float* dinv = (float*)ws;                 ws += sizeof(float) * N;
    float* xw_a = (float*)ws;                 ws += sizeof(float) * (size_t)N * HID;
    float* concat = (float*)ws;               ws += sizeof(float) * (size_t)N * DLAT;
    float* xw4 = (float*)ws;                  ws += sizeof(float) * N;
    // xw ping-pong: B-buffer aliases bedge (dead after sortlocal; N*128B == E*8B)
    float* xw_b = (float*)bedge;

    const int B = 256;

    // bucket partition (atomic range reservation) + LDS-resident per-bucket sort
    hipMemsetAsync(bucket_cnt, 0, sizeof(int) * MAXBKT, stream);
    binA_kernel<<<NB, B, 0, stream>>>(dst, bucket_cnt, E);
    bscan_kernel<<<1, MAXBKT, 0, stream>>>(bucket_cnt, bucket_start, cursor);
    binB_kernel<<<NB, B, 0, stream>>>(src, dst, ew, cursor, bedge, E);
    sortlocal_kernel<<<NBKT, B, 0, stream>>>(bedge, bucket_start, csr, row_start,
                                             dinv, N, E);

    // layer-1 xw, then fused agg+next-xw chain (1 node per 32-lane half)
    xw1_kernel<<<cdiv((long long)N * HID, B), B, 0, stream>>>(z, z_emb, Wg[0], dinv, xw_a, N);
    const int AGGB = cdiv((long long)N * 32, B);
    agg32f_kernel<0><<<AGGB, B, 0, stream>>>(row_start, csr, xw_a, bg[0], dinv, Wg[1],
                                             concat, 0, xw_b, N);
    agg32f_kernel<0><<<AGGB, B, 0, stream>>>(row_start, csr, xw_b, bg[1], dinv, Wg[2],
                                             concat, 32, xw_a, N);
    agg32f_kernel<1><<<AGGB, B, 0, stream>>>(row_start, csr, xw_a, bg[2], dinv, Wg[3],
                                             concat, 64, xw4, N);

    // fused layer-4 agg + tanh + top-30 + head
    topk_head_kernel<<<G, 128, 0, stream>>>(row_start, csr, xw4, bg[3], dinv, concat,
                                            Wc1, bc1, Wc2, bc2, Wl1, bl1, Wl2, bl2, out);
}